// Round 10
// baseline (332.840 us; speedup 1.0000x reference)
//
#include <hip/hip_runtime.h>
#include <math.h>

// Problem constants: B=4, N=1024, C=512, K=10, H=8, d=64
#define TOK_TOTAL 4096          // B*N
#define KNB 10
#define MATE 2097152            // 4096*512 elements

typedef __attribute__((ext_vector_type(8))) short short8;
typedef __attribute__((ext_vector_type(4))) float floatx4;
typedef unsigned short ushort;

__device__ __forceinline__ floatx4 mfma16(short8 a, short8 b, floatx4 c) {
  return __builtin_amdgcn_mfma_f32_16x16x32_bf16(a, b, c, 0, 0, 0);
}

__device__ __forceinline__ ushort f2bf(float f) {
  union { float f; unsigned int u; } x; x.f = f;
  unsigned int r = x.u + 0x7fffu + ((x.u >> 16) & 1u);
  return (ushort)(r >> 16);
}

__device__ __forceinline__ float bf2f(ushort u) {
  union { unsigned int u; float f; } x; x.u = ((unsigned int)u) << 16;
  return x.f;
}

__device__ __forceinline__ float lane_bcast(float v, int l) {
  union { float f; int i; } x; x.f = v;
  x.i = __builtin_amdgcn_readlane(x.i, l);
  return x.f;
}

// async global->LDS DMA, 16B/lane; LDS dest = wave-uniform base + lane*16
__device__ __forceinline__ void glds16(const ushort* g, ushort* l) {
  __builtin_amdgcn_global_load_lds((const __attribute__((address_space(1))) void*)g,
                                   (__attribute__((address_space(3))) void*)l, 16, 0, 0);
}

__device__ __forceinline__ float wave_reduce_sum(float v) {
#pragma unroll
  for (int m = 32; m >= 1; m >>= 1) v += __shfl_xor(v, m, 64);
  return v;
}

__device__ __forceinline__ float block_reduce_sum_256(float v, float* red) {
  v = wave_reduce_sum(v);
  __syncthreads();
  if ((threadIdx.x & 63) == 0) red[threadIdx.x >> 6] = v;
  __syncthreads();
  return red[0] + red[1] + red[2] + red[3];
}

// ---------------- one prep kernel: 5 weight transposes | wconv repack | bias pack |
// Q cast | accumulator-zeroing (folds the two hipMemsetAsync dispatches)
__global__ __launch_bounds__(256) void prep_kernel(const float* __restrict__ Wq,
                                                   const float* __restrict__ Wk,
                                                   const float* __restrict__ Wv,
                                                   const float* __restrict__ W2p,
                                                   const float* __restrict__ Wo,
                                                   const float* __restrict__ Wconv,
                                                   const float* __restrict__ Q,
                                                   const float* __restrict__ bq,
                                                   const float* __restrict__ bk,
                                                   const float* __restrict__ bv,
                                                   ushort* __restrict__ WT,   // 5x512x512
                                                   ushort* __restrict__ BcY,  // 5632x512
                                                   float* __restrict__ biasqkv,
                                                   ushort* __restrict__ Qb,
                                                   float* __restrict__ zbase, // kmean..Dx, 139360 f
                                                   float* __restrict__ loss) {
  int blk = blockIdx.x;
  if (blk < 1280) {
    __shared__ float tile[32][33];
    int zz = blk >> 8, rem = blk & 255;
    const float* W = (zz == 0) ? Wq : (zz == 1) ? Wk : (zz == 2) ? Wv
                     : (zz == 3) ? W2p : Wo;
    ushort* Wt = WT + (size_t)zz * 262144;
    int n0 = (rem & 15) * 32, k0 = (rem >> 4) * 32;
    int tx = threadIdx.x & 31, ty = threadIdx.x >> 5;  // 32 x 8
#pragma unroll
    for (int i = 0; i < 32; i += 8)
      tile[ty + i][tx] = W[(size_t)(k0 + ty + i) * 512 + n0 + tx];
    __syncthreads();
#pragma unroll
    for (int i = 0; i < 32; i += 8)
      Wt[(size_t)(n0 + ty + i) * 512 + k0 + tx] = f2bf(tile[tx][ty + i]);
  } else if (blk < 2304) {
    int i = (blk - 1280) * 256 + threadIdx.x;  // o*512+c
    const float* src = Wconv + (size_t)i * 11;
    int o = i >> 9, c = i & 511;
#pragma unroll
    for (int t = 0; t < 11; ++t)
      BcY[(((size_t)(t * 512 + o)) << 9) + c] = f2bf(src[t]);
  } else if (blk == 2304) {
    for (int i = threadIdx.x; i < 1536; i += 256)
      biasqkv[i] = (i < 512) ? bq[i] : ((i < 1024) ? bk[i - 512] : bv[i - 1024]);
  } else if (blk < 4353) {
    int i = (blk - 2305) * 256 + threadIdx.x;  // x4 floats
    float4 v = *(const float4*)(Q + (size_t)i * 4);
    Qb[(size_t)i * 4 + 0] = f2bf(v.x);
    Qb[(size_t)i * 4 + 1] = f2bf(v.y);
    Qb[(size_t)i * 4 + 2] = f2bf(v.z);
    Qb[(size_t)i * 4 + 3] = f2bf(v.w);
  } else {
    // zero kmean|kvbuf|Sv|Skv|Sx|Dv|Dkv|Dx (139360 floats = 34840 float4)
    int i = (blk - 4353) * 256 + threadIdx.x;
    if (i < 34840) {
      float4 z; z.x = 0.f; z.y = 0.f; z.z = 0.f; z.w = 0.f;
      ((float4*)zbase)[i] = z;
    }
    if (blk == 4353 && threadIdx.x == 0) loss[0] = 0.f;
  }
}

// ============ gemm128 v6: BM=BN=128, BK=32 — BARRIER-FREE wave-private pipelines.
// R0/R4/R6/R9 evidence: ~55us / MfmaUtil 16% invariant to BK, occupancy, A-direct,
// counted-vmcnt-3buf. All counters <35% busy -> the cost is the serial per-step
// chain (barrier -> ds_read -> MFMA -> barrier) convoyed across the block's 4
// waves (cooperative staging forces 2 barriers/step). Fix: each wave stages the
// 8 slabs IT reads (its 64 A-rows + 64 B-cols) into a PRIVATE 16KB LDS region ->
// zero s_barrier. Per-wave self-sync: vmcnt(8) (own batch landed, next in
// flight), ds_read, lgkmcnt(0) (reads drained -> buffer safe to overwrite),
// issue batch s+2, MFMA. No cross-wave hazard by construction. Staging traffic
// 2x (A/B slabs staged by 2 waves each) -- L2-absorbed. Fragment<->lane mapping
// identical to the verified kernel -> bit-identical output.
__global__ __launch_bounds__(256, 2) void gemm128(const ushort* __restrict__ A,
                                                  const ushort* __restrict__ Bt,
                                                  ushort* __restrict__ Cb,
                                                  int Ktot, int Ncols) {
  __shared__ __align__(16) ushort S[4][2][4096];  // [wave][buf][A 2048 | B 2048]
  int tid = threadIdx.x, w = tid >> 6, lane = tid & 63;
  int lm = lane & 15, kq = lane >> 4;
  int row0 = blockIdx.y * 128, col0 = blockIdx.x * 128;
  int wm = w >> 1, wn = w & 1;

  // 8 slab sources: 4 A slabs (rows wm*64+i*16) then 4 B slabs (cols wn*64+i*16)
  const ushort* gs[8];
#pragma unroll
  for (int i = 0; i < 4; ++i)
    gs[i] = A + (size_t)(row0 + wm * 64 + i * 16 + lm) * Ktot + kq * 8;
#pragma unroll
  for (int i = 0; i < 4; ++i)
    gs[4 + i] = Bt + (size_t)(col0 + wn * 64 + i * 16 + lm) * Ktot + kq * 8;

  ushort* buf0 = S[w][0];
  ushort* buf1 = S[w][1];

  floatx4 acc[4][4];
#pragma unroll
  for (int i = 0; i < 4; ++i)
#pragma unroll
    for (int j = 0; j < 4; ++j)
#pragma unroll
      for (int e = 0; e < 4; ++e) acc[i][j][e] = 0.f;

  // prologue: batch 0 -> buf0, batch 1 -> buf1 (8 glds16 each)
#pragma unroll
  for (int i = 0; i < 8; ++i) glds16(gs[i], buf0 + i * 512);
#pragma unroll
  for (int i = 0; i < 8; ++i) glds16(gs[i] + 32, buf1 + i * 512);

  int nsteps = Ktot >> 5;  // K=512 -> 16
  for (int s = 0; s < nsteps; ++s) {
    ushort* cur = (s & 1) ? buf1 : buf0;
    if (s + 1 < nsteps) {
      // outstanding = batch s (8, oldest) + batch s+1 (8): wait own batch s only
      asm volatile("s_waitcnt vmcnt(8)" ::: "memory");
    } else {
      asm volatile("s_waitcnt vmcnt(0)" ::: "memory");
    }
    short8 a[4], b[4];
#pragma unroll
    for (int mt = 0; mt < 4; ++mt)
      a[mt] = *(const short8*)(cur + mt * 512 + lane * 8);
#pragma unroll
    for (int nt = 0; nt < 4; ++nt)
      b[nt] = *(const short8*)(cur + 2048 + nt * 512 + lane * 8);
    // drain ds_reads so re-staging into `cur` cannot race them
    asm volatile("s_waitcnt lgkmcnt(0)" ::: "memory");
    if (s + 2 < nsteps) {
      int koff = (s + 2) << 5;
#pragma unroll
      for (int i = 0; i < 8; ++i) glds16(gs[i] + koff, cur + i * 512);
    }
#pragma unroll
    for (int mt = 0; mt < 4; ++mt)
#pragma unroll
      for (int nt = 0; nt < 4; ++nt)
        acc[mt][nt] = mfma16(a[mt], b[nt], acc[mt][nt]);
  }

#pragma unroll
  for (int mt = 0; mt < 4; ++mt) {
#pragma unroll
    for (int nt = 0; nt < 4; ++nt) {
      int col = col0 + wn * 64 + nt * 16 + lm;
#pragma unroll
      for (int r = 0; r < 4; ++r) {
        int row = row0 + wm * 64 + mt * 16 + kq * 4 + r;
        Cb[(size_t)row * Ncols + col] = f2bf(acc[mt][nt][r]);
      }
    }
  }
}

// ============ gemm128_qkv v3 (proven, R4): BK=32, N=1536 fixed, K=512 (16 steps)
__global__ __launch_bounds__(256, 4) void gemm128_qkv(const ushort* __restrict__ A,
                                                      const ushort* __restrict__ Bt,
                                                      const float* __restrict__ bias,
                                                      float* __restrict__ outf,
                                                      ushort* __restrict__ vb) {
  __shared__ __align__(16) ushort As[2][4096];
  __shared__ __align__(16) ushort Bs[2][4096];
  int tid = threadIdx.x, w = tid >> 6, lane = tid & 63;
  int lm = lane & 15, kq = lane >> 4;
  int row0 = blockIdx.y * 128, col0 = blockIdx.x * 128;
  int wm = w >> 1, wn = w & 1;

  bool isA = (w < 2);
  const ushort* gs[4];
  int go[4];
#pragma unroll
  for (int i = 0; i < 4; ++i) {
    int slab = (w & 1) * 4 + i;
    const ushort* base = isA ? (A + (size_t)(row0 + slab * 16 + lm) * 512)
                             : (Bt + (size_t)(col0 + slab * 16 + lm) * 512);
    gs[i] = base + kq * 8;
    go[i] = slab * 512;
  }

  floatx4 acc[4][4];
#pragma unroll
  for (int i = 0; i < 4; ++i)
#pragma unroll
    for (int j = 0; j < 4; ++j)
#pragma unroll
      for (int e = 0; e < 4; ++e) acc[i][j][e] = 0.f;

#pragma unroll
  for (int i = 0; i < 4; ++i)
    glds16(gs[i], (isA ? As[0] : Bs[0]) + go[i]);

  for (int s = 0; s < 16; ++s) {
    int buf = s & 1;
    __syncthreads();
    if (s + 1 < 16) {
      int koff = (s + 1) << 5;
      ushort* dst = (isA ? As[buf ^ 1] : Bs[buf ^ 1]);
#pragma unroll
      for (int i = 0; i < 4; ++i) glds16(gs[i] + koff, dst + go[i]);
    }
    short8 a[4], b[4];
#pragma unroll
    for (int mt = 0; mt < 4; ++mt)
      a[mt] = *(const short8*)(&As[buf][(wm * 4 + mt) * 512 + lane * 8]);
#pragma unroll
    for (int nt = 0; nt < 4; ++nt)
      b[nt] = *(const short8*)(&Bs[buf][(wn * 4 + nt) * 512 + lane * 8]);
#pragma unroll
    for (int mt = 0; mt < 4; ++mt)
#pragma unroll
      for (int nt = 0; nt < 4; ++nt)
        acc[mt][nt] = mfma16(a[mt], b[nt], acc[mt][nt]);
  }

#pragma unroll
  for (int mt = 0; mt < 4; ++mt) {
#pragma unroll
    for (int nt = 0; nt < 4; ++nt) {
      int col = col0 + wn * 64 + nt * 16 + lm;  // 0..1535
      int mat = col >> 9, cc = col & 511;
      float bs = bias[col];
#pragma unroll
      for (int r = 0; r < 4; ++r) {
        int row = row0 + wm * 64 + mt * 16 + kq * 4 + r;
        float val = acc[mt][nt][r] + bs;
        size_t idx = (size_t)row * 512 + cc;
        outf[(size_t)mat * MATE + idx] = val;
        if (mat == 2) vb[idx] = f2bf(val);
      }
    }
  }
}

// ---------------- conv gather: 2 rows/block, uint2 (4 bf16) per thread
__global__ __launch_bounds__(256) void gather_add_bias(const ushort* __restrict__ Y,
                                                       const int* __restrict__ adj,
                                                       const float* __restrict__ bias,
                                                       ushort* __restrict__ convb) {
  int n = (blockIdx.x << 1) + (threadIdx.x >> 7);
  int b10 = (n >> 10) << 10;
  int o = (threadIdx.x & 127) << 2;
  float4 bs = *(const float4*)(bias + o);
  float a0 = bs.x, a1 = bs.y, a2 = bs.z, a3 = bs.w;
#pragma unroll
  for (int t = 0; t < 11; ++t) {
    int src = (t == 0) ? n : (b10 + adj[(size_t)n * KNB + (t - 1)]);
    const ushort* p = Y + (size_t)src * 5632 + (size_t)t * 512 + o;
    uint2 u = *(const uint2*)p;
    a0 += bf2f((ushort)(u.x & 0xffff));
    a1 += bf2f((ushort)(u.x >> 16));
    a2 += bf2f((ushort)(u.y & 0xffff));
    a3 += bf2f((ushort)(u.y >> 16));
  }
  uint2 w;
  w.x = (unsigned)f2bf(a0) | ((unsigned)f2bf(a1) << 16);
  w.y = (unsigned)f2bf(a2) | ((unsigned)f2bf(a3) << 16);
  *(uint2*)(convb + (size_t)n * 512 + o) = w;
}

// ---------------- fallback chunked gather (TC<11): accumulate f32
__global__ __launch_bounds__(256) void gather_add(const ushort* __restrict__ Y,
                                                  const int* __restrict__ adj,
                                                  float* __restrict__ convf,
                                                  int t0, int ntaps, int ncols) {
  int n = blockIdx.x;
  int b10 = (n >> 10) << 10;
  int o = threadIdx.x * 2;
  float a0 = 0.f, a1 = 0.f;
  for (int t = t0; t < t0 + ntaps; ++t) {
    int src = (t == 0) ? n : (b10 + adj[(size_t)n * KNB + (t - 1)]);
    const ushort* p = Y + (size_t)src * ncols + (size_t)(t - t0) * 512 + o;
    a0 += bf2f(p[0]);
    a1 += bf2f(p[1]);
  }
  convf[(size_t)n * 512 + o] += a0;
  convf[(size_t)n * 512 + o + 1] += a1;
}

__global__ __launch_bounds__(256) void convbias_cast(const float* __restrict__ cf,
                                                     const float* __restrict__ bias,
                                                     ushort* __restrict__ cb) {
  int i = blockIdx.x * 256 + threadIdx.x;
  float4 v = *(const float4*)(cf + (size_t)i * 4);
  int c = (i * 4) & 511;
  cb[(size_t)i * 4 + 0] = f2bf(v.x + bias[c + 0]);
  cb[(size_t)i * 4 + 1] = f2bf(v.y + bias[c + 1]);
  cb[(size_t)i * 4 + 2] = f2bf(v.z + bias[c + 2]);
  cb[(size_t)i * 4 + 3] = f2bf(v.w + bias[c + 3]);
}

// ============ gemm64: BM=64,BN=64,BK=64; 4 waves (2x2), wave 32x32 ============
__global__ __launch_bounds__(256) void gemm64(const ushort* __restrict__ A,
                                              const ushort* __restrict__ Bt,
                                              const float* __restrict__ bias,
                                              float* __restrict__ Cf,
                                              ushort* __restrict__ Cb,
                                              int Ktot) {
  __shared__ __align__(16) ushort As[2][4096];
  __shared__ __align__(16) ushort Bs[2][4096];
  int tid = threadIdx.x, w = tid >> 6, lane = tid & 63;
  int lm = lane & 15, kq = lane >> 4;
  int row0 = blockIdx.y * 64, col0 = blockIdx.x * 64;
  int wm = w >> 1, wn = w & 1;

  const ushort* gsrc[4];
  int goff[4];
  bool isA = (w < 2);
#pragma unroll
  for (int i = 0; i < 4; ++i) {
    int l = w * 4 + i, t, j;
    const ushort* base;
    if (l < 8) { t = l >> 1; j = l & 1; base = A + (size_t)(row0 + t * 16 + lm) * Ktot; }
    else { int lb = l - 8; t = lb >> 1; j = lb & 1; base = Bt + (size_t)(col0 + t * 16 + lm) * Ktot; }
    gsrc[i] = base + j * 32 + kq * 8;
    goff[i] = t * 1024 + j * 512;
  }

  floatx4 acc[2][2];
#pragma unroll
  for (int i = 0; i < 2; ++i)
#pragma unroll
    for (int j = 0; j < 2; ++j)
#pragma unroll
      for (int e = 0; e < 4; ++e) acc[i][j][e] = 0.f;

#pragma unroll
  for (int i = 0; i < 4; ++i)
    glds16(gsrc[i], (isA ? As[0] : Bs[0]) + goff[i]);

  int nsteps = Ktot >> 6;
  for (int s = 0; s < nsteps; ++s) {
    int buf = s & 1;
    __syncthreads();
    if (s + 1 < nsteps) {
      int koff = (s + 1) << 6;
      ushort* dst = (isA ? As[buf ^ 1] : Bs[buf ^ 1]);
#pragma unroll
      for (int i = 0; i < 4; ++i) glds16(gsrc[i] + koff, dst + goff[i]);
    }
#pragma unroll
    for (int j = 0; j < 2; ++j) {
      short8 a0 = *(const short8*)(&As[buf][(wm * 2 + 0) * 1024 + j * 512 + lane * 8]);
      short8 a1 = *(const short8*)(&As[buf][(wm * 2 + 1) * 1024 + j * 512 + lane * 8]);
      short8 b0 = *(const short8*)(&Bs[buf][(wn * 2 + 0) * 1024 + j * 512 + lane * 8]);
      short8 b1 = *(const short8*)(&Bs[buf][(wn * 2 + 1) * 1024 + j * 512 + lane * 8]);
      acc[0][0] = mfma16(a0, b0, acc[0][0]);
      acc[0][1] = mfma16(a0, b1, acc[0][1]);
      acc[1][0] = mfma16(a1, b0, acc[1][0]);
      acc[1][1] = mfma16(a1, b1, acc[1][1]);
    }
  }

  int colb = col0 + wn * 32;
  int rowb = row0 + wm * 32 + kq * 4;
#pragma unroll
  for (int mt = 0; mt < 2; ++mt) {
#pragma unroll
    for (int nt = 0; nt < 2; ++nt) {
      int col = colb + nt * 16 + lm;
      float bs = bias[col];
#pragma unroll
      for (int r = 0; r < 4; ++r) {
        int row = rowb + mt * 16 + r;
        float val = acc[mt][nt][r] + bs;
        size_t idx = (size_t)row * 512 + col;
        if (Cf) Cf[idx] = val;
        if (Cb) Cb[idx] = f2bf(val);
      }
    }
  }
}

// ---------------- fused relu+eps, /softplus(scale), focus (in-place); q0||k0 contiguous
__global__ __launch_bounds__(256) void focus_kernel(float* __restrict__ x,
                                                    const float* __restrict__ scale_p) {
  __shared__ float red[4];
  int row = blockIdx.x;  // 0..8191 covers q0 then k0
  float* p = x + (size_t)row * 512;
  int tid = threadIdx.x;
  float sp0 = scale_p[tid], sp1 = scale_p[tid + 256];
  float sc0 = sp0 > 20.f ? sp0 : log1pf(expf(sp0));
  float sc1 = sp1 > 20.f ? sp1 : log1pf(expf(sp1));
  float v0 = (fmaxf(p[tid], 0.f) + 1e-6f) / sc0;
  float v1 = (fmaxf(p[tid + 256], 0.f) + 1e-6f) / sc1;
  float tot = block_reduce_sum_256(v0 * v0 + v1 * v1, red);
  float n = sqrtf(tot);
  float np = n + 1e-6f;
  float f = n / (np * np * np);
  p[tid] = v0 * v0 * v0 * f;
  p[tid + 256] = v1 * v1 * v1 * f;
}

// ---------------- kv split-K x8 (256 blocks) + fused disagree-v + fused kmean
__global__ __launch_bounds__(256) void kv_kernel(const float* __restrict__ kf,
                                                 const float* __restrict__ v,
                                                 float* __restrict__ kv,
                                                 float* __restrict__ Sacc,
                                                 float* __restrict__ Dacc,
                                                 float* __restrict__ kmean) {
  __shared__ float Ks[16][64];
  __shared__ float Vs[16][64];
  __shared__ float Spart[64];
  __shared__ float Kpart[64];
  __shared__ float Dpart;
  int bh = blockIdx.x >> 3, chunk = blockIdx.x & 7;
  int b = bh >> 3, h = bh & 7;
  int tid = threadIdx.x;
  int lr = tid >> 4, lc = (tid & 15) << 2;
  int tx = tid & 15, ty = tid >> 4;
  if (tid < 64) { Spart[tid] = 0.f; Kpart[tid] = 0.f; }
  if (tid == 0) Dpart = 0.f;
  __syncthreads();
  const float* kbase = kf + (size_t)b * 524288 + h * 64 + (size_t)chunk * 128 * 512;
  const float* vbase = v + (size_t)b * 524288 + h * 64 + (size_t)chunk * 128 * 512;
  float acc[4][4] = {};
  float Sloc[4] = {0.f, 0.f, 0.f, 0.f};
  float Kloc[4] = {0.f, 0.f, 0.f, 0.f};
  float Dloc = 0.f;
  for (int n0 = 0; n0 < 128; n0 += 16) {
    float4 ke = *(const float4*)(kbase + (size_t)(n0 + lr) * 512 + lc);
    *(float4*)(&Ks[lr][lc]) = ke;
    Kloc[0] += ke.x; Kloc[1] += ke.y; Kloc[2] += ke.z; Kloc[3] += ke.w;
    float4 ve = *(const float4*)(vbase + (size_t)(n0 + lr) * 512 + lc);
    *(float4*)(&Vs[lr][lc]) = ve;
    __syncthreads();
    // disagree-v on this tile: 16-lane group reduce (threads sharing row lr)
    float sq = ve.x * ve.x + ve.y * ve.y + ve.z * ve.z + ve.w * ve.w;
#pragma unroll
    for (int m = 1; m < 16; m <<= 1) sq += __shfl_xor(sq, m, 64);
    float cn = fmaxf(sqrtf(sq), 1e-12f);
    Sloc[0] += ve.x / cn; Sloc[1] += ve.y / cn;
    Sloc[2] += ve.z / cn; Sloc[3] += ve.w / cn;
    if ((tid & 15) == 0) Dloc += sq / (cn * cn);
#pragma unroll
    for (int kk = 0; kk < 16; ++kk) {
      float a[4], bb[4];
#pragma unroll
      for (int i = 0; i < 4; ++i) a[i] = Ks[kk][ty * 4 + i];
#pragma unroll
      for (int j = 0; j < 4; ++j) bb[j] = Vs[kk][tx * 4 + j];
#pragma unroll
      for (int i = 0; i < 4; ++i)
#pragma unroll
        for (int j = 0; j < 4; ++j) acc[i][j] += a[i] * bb[j];
    }
    __syncthreads();
  }
#pragma unroll
  for (int i = 0; i < 4; ++i)
#pragma unroll
    for (int j = 0; j < 4; ++j)
      atomicAdd(&kv[(size_t)bh * 4096 + (ty * 4 + i) * 64 + tx * 4 + j],
                acc[i][j] * (1.f / 1024.f));
  // accumulate disagree-v + kmean partials: LDS then one global set
#pragma unroll
  for (int i = 0; i < 4; ++i) {
    atomicAdd(&Spart[lc + i], Sloc[i]);
    atomicAdd(&Kpart[lc + i], Kloc[i]);
  }
  if ((tid & 15) == 0) atomicAdd(&Dpart, Dloc);
  __syncthreads();
  if (tid < 64) {
    atomicAdd(&Sacc[bh * 64 + tid], Spart[tid]);
    atomicAdd(&kmean[b * 512 + h * 64 + tid], Kpart[tid] * (1.f / 1024.f));
  }
  if (tid == 64) atomicAdd(&Dacc[bh], Dpart);
}

// ---------------- fused attn-out + z + LN + disagree-x (+disagree-kv on 4 blocks)
__global__ __launch_bounds__(512, 4) void attn_ln_kernel(const float* __restrict__ qf,
                                                         const float* __restrict__ kvf,
                                                         const float* __restrict__ kmean,
                                                         const float* __restrict__ x_local,
                                                         const float* __restrict__ g,
                                                         const float* __restrict__ bp,
                                                         ushort* __restrict__ xn,
                                                         float* __restrict__ Sacc,
                                                         float* __restrict__ Dacc,
                                                         float* __restrict__ Skv,
                                                         float* __restrict__ Dkv) {
  __shared__ __align__(16) ushort kvs[32768];  // [h][dd][e] bf16, 64 KB
  __shared__ float red[16];                    // 8 sums | 8 sumsqs
  __shared__ float Sl[8][64];
  __shared__ float Dl[8];
  int r0 = blockIdx.x << 3;       // first of 8 rows
  int b = r0 >> 10;
  int c = threadIdx.x, wv = c >> 6, lane = c & 63;
  // stage kv[b] f32 -> bf16 LDS (32768 elems), coalesced float4
  const float4* kvg = (const float4*)(kvf + (size_t)b * 32768);
#pragma unroll
  for (int i = 0; i < 16; ++i) {
    float4 kvv = kvg[c + i * 512];
    int o = (c + i * 512) << 2;
    kvs[o + 0] = f2bf(kvv.x); kvs[o + 1] = f2bf(kvv.y);
    kvs[o + 2] = f2bf(kvv.z); kvs[o + 3] = f2bf(kvv.w);
  }
  float kmr = kmean[b * 512 + c];
  float gr = g[c], bpr = bp[c];
  __syncthreads();
  // one-time: pull this thread's kv column, packed 2 bf16 per uint (32 VGPRs)
  unsigned int kvr[32];
#pragma unroll
  for (int i = 0; i < 32; ++i) {
    unsigned int lo = kvs[wv * 4096 + (2 * i) * 64 + lane];
    unsigned int hi = kvs[wv * 4096 + (2 * i + 1) * 64 + lane];
    kvr[i] = lo | (hi << 16);
  }
  float Sreg = 0.f, Dreg = 0.f;
  for (int r = 0; r < 8; ++r) {
    int row = r0 + r;
    float qv = qf[(size_t)row * 512 + c];
    float xl = x_local[(size_t)row * 512 + c];
    // z = 1/(dot(q_head, kmean_head)+eps), per wave
    float zd = wave_reduce_sum(qv * kmr);
    float zz = 1.f / (zd + 1e-6f);
    // dot via readlane broadcast + packed register kv column — no LDS
    float s = 0.f;
#pragma unroll
    for (int i = 0; i < 32; ++i) {
      union { unsigned int u; float f; } lo, hi;
      lo.u = kvr[i] << 16;
      hi.u = kvr[i] & 0xffff0000u;
      s += lane_bcast(qv, 2 * i) * lo.f;
      s += lane_bcast(qv, 2 * i + 1) * hi.f;
    }
    float xv = s * zz + xl;
    // single-pass LN stats: block sum + sumsq
    float s1 = wave_reduce_sum(xv);
    float s2 = wave_reduce_sum(xv * xv);       // also the sub-vector norm^2
    if (lane == 0) { red[wv] = s1; red[8 + wv] = s2; }
    __syncthreads();
    float tsum = red[0] + red[1] + red[2] + red[3] + red[4] + red[5] + red[6] + red[7];
    float tsq = red[8] + red[9] + red[10] + red[11] + red[12] + red[13] + red[14] + red[15];
    __syncthreads();                           // red consumed before next row
    float mu = tsum * (1.f / 512.f);
    float var = tsq * (1.f / 512.f) - mu * mu;
    float inv = rsqrtf(fmaxf(var, 0.f) + 1e-5f);
    xn[(size_t)row * 512 + c] = f2bf((xv - mu) * inv * gr + bpr);
    // disagreement on x
    float norm = fmaxf(sqrtf(s2), 1e-12f);
    Sreg += xv / norm;
    Dreg += s2 / (norm * norm);
  }
  Sl[wv][lane] = Sreg;
  if (lane == 0) Dl[wv] = Dreg;
  __syncthreads();
  int gx = b * 8 + ((r0 & 1023) >> 7);
  if (c < 64) {
    float ssum = 0.f;
#pragma unroll
    for (int ww = 0; ww < 8; ++ww) ssum += Sl[ww][c];
    atomicAdd(&Sacc[gx * 64 + c], ssum);
  } else if (c == 64) {
    float dsum = 0.f;
#pragma unroll
    for (int ww = 0; ww < 8; ++ww) dsum += Dl[ww];
    atomicAdd(&Dacc[gx], dsum);
  }
  // disagree-kv: one block per batch; wave wv = head; vals from packed regs
  if ((blockIdx.x & 127) == 0) {
    float S2 = 0.f, D2 = 0.f;
#pragma unroll
    for (int i = 0; i < 32; ++i) {
      union { unsigned int u; float f; } lo, hi;
      lo.u = kvr[i] << 16;
      hi.u = kvr[i] & 0xffff0000u;
      float sq = wave_reduce_sum(lo.f * lo.f);
      float nrm = fmaxf(sqrtf(sq), 1e-12f);
      float hn = lo.f / nrm;
      S2 += hn; D2 += hn * hn;
      sq = wave_reduce_sum(hi.f * hi.f);
      nrm = fmaxf(sqrtf(sq), 1e-12f);
      hn = hi.f / nrm;
      S2 += hn; D2 += hn * hn;
    }
    float dt = wave_reduce_sum(D2);
    atomicAdd(&Skv[(b * 8 + wv) * 64 + lane], S2);
    if (lane == 0) atomicAdd(&Dkv[b * 8 + wv], dt);
  }
}

// ---------------- disagreement finals, all 3 sets in parallel (96 blocks)
__global__ __launch_bounds__(64) void disagree_final_all(const float* __restrict__ Sall,
                                                         const float* __restrict__ Dall,
                                                         float s0, float s1, float s2,
                                                         float* __restrict__ loss) {
  int set = blockIdx.x >> 5, gg = blockIdx.x & 31;
  int l = threadIdx.x;
  float sv = Sall[set * 2048 + gg * 64 + l];
  float sim = wave_reduce_sum(sv * sv);
  if (l == 0) {
    float scale = (set == 0) ? s0 : (set == 1) ? s1 : s2;
    atomicAdd(loss, (sim - Dall[set * 32 + gg]) * scale);
  }
}

extern "C" void kernel_launch(void* const* d_in, const int* in_sizes, int n_in,
                              void* d_out, int out_size, void* d_ws, size_t ws_size,
                              hipStream_t stream) {
  const float* Q       = (const float*)d_in[0];
  const int*   adj     = (const int*)d_in[1];
  const float* Wq      = (const float*)d_in[2];
  const float* bq      = (const float*)d_in[3];
  const float* Wk      = (const float*)d_in[4];
  const float* bk      = (const float*)d_in[5];
  const float* Wv      = (const float*)d_in[6];
  const float* bv      = (const float*)d_in[7];
  const float* scale_p = (const float*)d_in[8];
  const float* Wconv   = (const float*)d_in[9];
  const float* bconv   = (const float*)d_in[10];
  const float* W2      = (const float*)d_in[11];
  const float* b2      = (const float*)d_in[12];
  const float* ln_g    = (const float*)d_in[13];
  const float* ln_b    = (const float*)d_in[14];
  const float* Wo      = (const float*)d_in[15];
  const float* bo      = (const float*)d_in[16];

  float* out = (float*)d_out;
  float* loss_slot = out + MATE;

  float* ws = (float*)d_ws;
  float* q0      = ws;                 // f32; k0, v contiguous (qkv fused epilogue)
  float* k0      = q0 + MATE;
  float* v       = k0 + MATE;
  float* x_local = v + MATE;
  float* convf   = x_local + MATE;     // fallback accum only (TC<11)
  ushort* Qb    = (ushort*)(convf + MATE);
  ushort* vb    = Qb + MATE;
  ushort* convb = vb + MATE;
  ushort* xnb   = convb + MATE;
  ushort* WqT   = xnb + MATE;          // Wq|Wk|Wv transposed, contiguous (N=1536)
  ushort* W2T   = WqT + 3 * 262144;
  ushort* WoT   = W2T + 262144;
  ushort* BcY   = WoT + 262144;        // 5632 x 512 (Bt layout for Y-GEMM)
  float* biasqkv = (float*)(BcY + 5632 * 512);
  float* kmean = biasqkv + 1536;
  float* kvbuf = kmean + 2048;         // 131072 (zeroed)
  float* Sv    = kvbuf + 131072;       // Sv|Skv|Sx contiguous
  float* Skv   = Sv + 2048;
  float* Sx    = Skv + 2048;
  float* Dv    = Sx + 2048;            // Dv|Dkv|Dx contiguous
  float* Dkv   = Dv + 32;
  float* Dx    = Dkv + 32;
  float* ytail = Dx + 32;
  ushort* Ybf  = (ushort*)ytail;       // Y buffer: TC taps x 4096 x 512 bf16

  size_t used_floats = (size_t)(ytail - ws);
  size_t avail_floats = (ws_size / 4 > used_floats) ? (ws_size / 4 - used_floats) : 0;
  int TC = (int)(avail_floats / (MATE / 2));
  if (TC < 1) TC = 1;
  if (TC > 11) TC = 11;

  // all one-time repacks + accumulator zeroing in one launch (memsets folded)
  prep_kernel<<<4490, 256, 0, stream>>>(Wq, Wk, Wv, W2, Wo, Wconv, Q,
                                        bq, bk, bv, WqT, BcY, biasqkv, Qb,
                                        kmean, loss_slot);

  // fused q,k,v: 128x128 tile BK=32, N=1536, grid 12x32 = 384 blocks
  gemm128_qkv<<<dim3(12, 32), 256, 0, stream>>>(Qb, WqT, biasqkv, q0, vb);

  // conv: Y = vb @ Wcat (M=4096, N=5632, K=512), then gather(+bias) -> convb
  if (TC >= 11) {
    gemm128<<<dim3(44, 32), 256, 0, stream>>>(vb, BcY, Ybf, 512, 5632);
    gather_add_bias<<<2048, 256, 0, stream>>>(Ybf, adj, bconv, convb);
  } else {
    hipMemsetAsync(convf, 0, MATE * sizeof(float), stream);
    for (int t0 = 0; t0 < 11; t0 += TC) {
      int nt = (11 - t0 < TC) ? (11 - t0) : TC;
      int ncols = nt * 512;
      gemm128<<<dim3(ncols / 128, 32), 256, 0, stream>>>(
          vb, BcY + (size_t)(t0 * 512) * 512, Ybf, 512, ncols);
      gather_add<<<4096, 256, 0, stream>>>(Ybf, adj, convf, t0, nt, ncols);
    }
    convbias_cast<<<2048, 256, 0, stream>>>(convf, bconv, convb);
  }

  gemm64<<<dim3(8, 64), 256, 0, stream>>>(convb, W2T, b2, x_local, nullptr, 512);

  // focus on q0 and k0 in one launch (contiguous buffers)
  focus_kernel<<<2 * TOK_TOTAL, 256, 0, stream>>>(q0, scale_p);

  // kv + fused disagree-v + fused kmean
  kv_kernel<<<256, 256, 0, stream>>>(k0, v, kvbuf, Sv, Dv, kmean);

  // fused attention-out + z + LayerNorm + disagree-x + disagree-kv
  attn_ln_kernel<<<512, 512, 0, stream>>>(q0, kvbuf, kmean, x_local,
                                          ln_g, ln_b, xnb, Sx, Dx, Skv, Dkv);

  disagree_final_all<<<96, 64, 0, stream>>>(Sv, Dv,
                                            1.f / (33554432.f * 3.f),
                                            1.f / (131072.f * 3.f),
                                            1.f / (33554432.f * 3.f), loss_slot);

  gemm64<<<dim3(8, 64), 256, 0, stream>>>(xnb, WoT, bo, out, nullptr, 512);
}

// Round 11
// 288.102 us; speedup vs baseline: 1.1553x; 1.1553x over previous
//
#include <hip/hip_runtime.h>
#include <math.h>

// Problem constants: B=4, N=1024, C=512, K=10, H=8, d=64
#define TOK_TOTAL 4096          // B*N
#define KNB 10
#define MATE 2097152            // 4096*512 elements

typedef __attribute__((ext_vector_type(8))) short short8;
typedef __attribute__((ext_vector_type(4))) float floatx4;
typedef unsigned short ushort;

__device__ __forceinline__ floatx4 mfma16(short8 a, short8 b, floatx4 c) {
  return __builtin_amdgcn_mfma_f32_16x16x32_bf16(a, b, c, 0, 0, 0);
}

__device__ __forceinline__ ushort f2bf(float f) {
  union { float f; unsigned int u; } x; x.f = f;
  unsigned int r = x.u + 0x7fffu + ((x.u >> 16) & 1u);
  return (ushort)(r >> 16);
}

__device__ __forceinline__ float bf2f(ushort u) {
  union { unsigned int u; float f; } x; x.u = ((unsigned int)u) << 16;
  return x.f;
}

__device__ __forceinline__ float lane_bcast(float v, int l) {
  union { float f; int i; } x; x.f = v;
  x.i = __builtin_amdgcn_readlane(x.i, l);
  return x.f;
}

// async global->LDS DMA, 16B/lane; LDS dest = wave-uniform base + lane*16
__device__ __forceinline__ void glds16(const ushort* g, ushort* l) {
  __builtin_amdgcn_global_load_lds((const __attribute__((address_space(1))) void*)g,
                                   (__attribute__((address_space(3))) void*)l, 16, 0, 0);
}

__device__ __forceinline__ float wave_reduce_sum(float v) {
#pragma unroll
  for (int m = 32; m >= 1; m >>= 1) v += __shfl_xor(v, m, 64);
  return v;
}

__device__ __forceinline__ float block_reduce_sum_256(float v, float* red) {
  v = wave_reduce_sum(v);
  __syncthreads();
  if ((threadIdx.x & 63) == 0) red[threadIdx.x >> 6] = v;
  __syncthreads();
  return red[0] + red[1] + red[2] + red[3];
}

// ---------------- one prep kernel: 5 weight transposes | wconv repack | bias pack |
// Q cast | accumulator-zeroing (folds the two hipMemsetAsync dispatches)
__global__ __launch_bounds__(256) void prep_kernel(const float* __restrict__ Wq,
                                                   const float* __restrict__ Wk,
                                                   const float* __restrict__ Wv,
                                                   const float* __restrict__ W2p,
                                                   const float* __restrict__ Wo,
                                                   const float* __restrict__ Wconv,
                                                   const float* __restrict__ Q,
                                                   const float* __restrict__ bq,
                                                   const float* __restrict__ bk,
                                                   const float* __restrict__ bv,
                                                   ushort* __restrict__ WT,   // 5x512x512
                                                   ushort* __restrict__ BcY,  // 5632x512
                                                   float* __restrict__ biasqkv,
                                                   ushort* __restrict__ Qb,
                                                   float* __restrict__ zbase, // kmean..Dx, 139360 f
                                                   float* __restrict__ loss) {
  int blk = blockIdx.x;
  if (blk < 1280) {
    __shared__ float tile[32][33];
    int zz = blk >> 8, rem = blk & 255;
    const float* W = (zz == 0) ? Wq : (zz == 1) ? Wk : (zz == 2) ? Wv
                     : (zz == 3) ? W2p : Wo;
    ushort* Wt = WT + (size_t)zz * 262144;
    int n0 = (rem & 15) * 32, k0 = (rem >> 4) * 32;
    int tx = threadIdx.x & 31, ty = threadIdx.x >> 5;  // 32 x 8
#pragma unroll
    for (int i = 0; i < 32; i += 8)
      tile[ty + i][tx] = W[(size_t)(k0 + ty + i) * 512 + n0 + tx];
    __syncthreads();
#pragma unroll
    for (int i = 0; i < 32; i += 8)
      Wt[(size_t)(n0 + ty + i) * 512 + k0 + tx] = f2bf(tile[tx][ty + i]);
  } else if (blk < 2304) {
    int i = (blk - 1280) * 256 + threadIdx.x;  // o*512+c
    const float* src = Wconv + (size_t)i * 11;
    int o = i >> 9, c = i & 511;
#pragma unroll
    for (int t = 0; t < 11; ++t)
      BcY[(((size_t)(t * 512 + o)) << 9) + c] = f2bf(src[t]);
  } else if (blk == 2304) {
    for (int i = threadIdx.x; i < 1536; i += 256)
      biasqkv[i] = (i < 512) ? bq[i] : ((i < 1024) ? bk[i - 512] : bv[i - 1024]);
  } else if (blk < 4353) {
    int i = (blk - 2305) * 256 + threadIdx.x;  // x4 floats
    float4 v = *(const float4*)(Q + (size_t)i * 4);
    Qb[(size_t)i * 4 + 0] = f2bf(v.x);
    Qb[(size_t)i * 4 + 1] = f2bf(v.y);
    Qb[(size_t)i * 4 + 2] = f2bf(v.z);
    Qb[(size_t)i * 4 + 3] = f2bf(v.w);
  } else {
    // zero kmean|kvbuf|Sv|Skv|Sx|Dv|Dkv|Dx (139360 floats = 34840 float4)
    int i = (blk - 4353) * 256 + threadIdx.x;
    if (i < 34840) {
      float4 z; z.x = 0.f; z.y = 0.f; z.z = 0.f; z.w = 0.f;
      ((float4*)zbase)[i] = z;
    }
    if (blk == 4353 && threadIdx.x == 0) loss[0] = 0.f;
  }
}

// ============ gemm128 v5 (measured best, R9: 54.6us): BM=BN=128, BK=32; 3-buffer
// LDS, depth-2 prefetch, COUNTED vmcnt. Six structural variants (BK 32/64, occ
// 2-4 blk/CU, A-direct, barrier-free) all land >=54.6us -> 128^2 structure is
// pinned here; do not micro-optimize further.
__global__ __launch_bounds__(256, 3) void gemm128(const ushort* __restrict__ A,
                                                  const ushort* __restrict__ Bt,
                                                  ushort* __restrict__ Cb,
                                                  int Ktot, int Ncols) {
  __shared__ __align__(16) ushort As[3][4096];
  __shared__ __align__(16) ushort Bs[3][4096];
  int tid = threadIdx.x, w = tid >> 6, lane = tid & 63;
  int lm = lane & 15, kq = lane >> 4;
  int row0 = blockIdx.y * 128, col0 = blockIdx.x * 128;
  int wm = w >> 1, wn = w & 1;

  bool isA = (w < 2);
  const ushort* gs[4];
  int go[4];
#pragma unroll
  for (int i = 0; i < 4; ++i) {
    int slab = (w & 1) * 4 + i;
    const ushort* base = isA ? (A + (size_t)(row0 + slab * 16 + lm) * Ktot)
                             : (Bt + (size_t)(col0 + slab * 16 + lm) * Ktot);
    gs[i] = base + kq * 8;
    go[i] = slab * 512;
  }

  floatx4 acc[4][4];
#pragma unroll
  for (int i = 0; i < 4; ++i)
#pragma unroll
    for (int j = 0; j < 4; ++j)
#pragma unroll
      for (int e = 0; e < 4; ++e) acc[i][j][e] = 0.f;

  // prologue: stage batches 0 and 1 (4 loads each per wave)
#pragma unroll
  for (int i = 0; i < 4; ++i) glds16(gs[i], (isA ? As[0] : Bs[0]) + go[i]);
#pragma unroll
  for (int i = 0; i < 4; ++i) glds16(gs[i] + 32, (isA ? As[1] : Bs[1]) + go[i]);
  asm volatile("s_waitcnt vmcnt(4)" ::: "memory");  // batch 0 landed; batch 1 in flight
  __builtin_amdgcn_s_barrier();

  int nsteps = Ktot >> 5;  // >= 2 for all call sites (K=512 -> 16)
  for (int s = 0; s < nsteps; ++s) {
    int cur = s % 3;
    if (s + 2 < nsteps) {
      int nb = (s + 2) % 3;
      ushort* dst = (isA ? As[nb] : Bs[nb]);
      int koff = (s + 2) << 5;
#pragma unroll
      for (int i = 0; i < 4; ++i) glds16(gs[i] + koff, dst + go[i]);
    }
    const ushort* Acur = As[cur];
    const ushort* Bcur = Bs[cur];
    short8 a[4], b[4];
#pragma unroll
    for (int mt = 0; mt < 4; ++mt)
      a[mt] = *(const short8*)(&Acur[(wm * 4 + mt) * 512 + lane * 8]);
#pragma unroll
    for (int nt = 0; nt < 4; ++nt)
      b[nt] = *(const short8*)(&Bcur[(wn * 4 + nt) * 512 + lane * 8]);
#pragma unroll
    for (int mt = 0; mt < 4; ++mt)
#pragma unroll
      for (int nt = 0; nt < 4; ++nt)
        acc[mt][nt] = mfma16(a[mt], b[nt], acc[mt][nt]);
    if (s + 1 < nsteps) {
      if (s + 2 < nsteps) {
        asm volatile("s_waitcnt vmcnt(4)" ::: "memory");
      } else {
        asm volatile("s_waitcnt vmcnt(0)" ::: "memory");
      }
      __builtin_amdgcn_s_barrier();
    }
  }

#pragma unroll
  for (int mt = 0; mt < 4; ++mt) {
#pragma unroll
    for (int nt = 0; nt < 4; ++nt) {
      int col = col0 + wn * 64 + nt * 16 + lm;
#pragma unroll
      for (int r = 0; r < 4; ++r) {
        int row = row0 + wm * 64 + mt * 16 + kq * 4 + r;
        Cb[(size_t)row * Ncols + col] = f2bf(acc[mt][nt][r]);
      }
    }
  }
}

// ============ gemm128_qkv v3 (proven, R4): BK=32, N=1536 fixed, K=512 (16 steps)
__global__ __launch_bounds__(256, 4) void gemm128_qkv(const ushort* __restrict__ A,
                                                      const ushort* __restrict__ Bt,
                                                      const float* __restrict__ bias,
                                                      float* __restrict__ outf,
                                                      ushort* __restrict__ vb) {
  __shared__ __align__(16) ushort As[2][4096];
  __shared__ __align__(16) ushort Bs[2][4096];
  int tid = threadIdx.x, w = tid >> 6, lane = tid & 63;
  int lm = lane & 15, kq = lane >> 4;
  int row0 = blockIdx.y * 128, col0 = blockIdx.x * 128;
  int wm = w >> 1, wn = w & 1;

  bool isA = (w < 2);
  const ushort* gs[4];
  int go[4];
#pragma unroll
  for (int i = 0; i < 4; ++i) {
    int slab = (w & 1) * 4 + i;
    const ushort* base = isA ? (A + (size_t)(row0 + slab * 16 + lm) * 512)
                             : (Bt + (size_t)(col0 + slab * 16 + lm) * 512);
    gs[i] = base + kq * 8;
    go[i] = slab * 512;
  }

  floatx4 acc[4][4];
#pragma unroll
  for (int i = 0; i < 4; ++i)
#pragma unroll
    for (int j = 0; j < 4; ++j)
#pragma unroll
      for (int e = 0; e < 4; ++e) acc[i][j][e] = 0.f;

#pragma unroll
  for (int i = 0; i < 4; ++i)
    glds16(gs[i], (isA ? As[0] : Bs[0]) + go[i]);

  for (int s = 0; s < 16; ++s) {
    int buf = s & 1;
    __syncthreads();
    if (s + 1 < 16) {
      int koff = (s + 1) << 5;
      ushort* dst = (isA ? As[buf ^ 1] : Bs[buf ^ 1]);
#pragma unroll
      for (int i = 0; i < 4; ++i) glds16(gs[i] + koff, dst + go[i]);
    }
    short8 a[4], b[4];
#pragma unroll
    for (int mt = 0; mt < 4; ++mt)
      a[mt] = *(const short8*)(&As[buf][(wm * 4 + mt) * 512 + lane * 8]);
#pragma unroll
    for (int nt = 0; nt < 4; ++nt)
      b[nt] = *(const short8*)(&Bs[buf][(wn * 4 + nt) * 512 + lane * 8]);
#pragma unroll
    for (int mt = 0; mt < 4; ++mt)
#pragma unroll
      for (int nt = 0; nt < 4; ++nt)
        acc[mt][nt] = mfma16(a[mt], b[nt], acc[mt][nt]);
  }

#pragma unroll
  for (int mt = 0; mt < 4; ++mt) {
#pragma unroll
    for (int nt = 0; nt < 4; ++nt) {
      int col = col0 + wn * 64 + nt * 16 + lm;  // 0..1535
      int mat = col >> 9, cc = col & 511;
      float bs = bias[col];
#pragma unroll
      for (int r = 0; r < 4; ++r) {
        int row = row0 + wm * 64 + mt * 16 + kq * 4 + r;
        float val = acc[mt][nt][r] + bs;
        size_t idx = (size_t)row * 512 + cc;
        outf[(size_t)mat * MATE + idx] = val;
        if (mat == 2) vb[idx] = f2bf(val);
      }
    }
  }
}

// ---------------- conv gather: 2 rows/block, uint2 (4 bf16) per thread
__global__ __launch_bounds__(256) void gather_add_bias(const ushort* __restrict__ Y,
                                                       const int* __restrict__ adj,
                                                       const float* __restrict__ bias,
                                                       ushort* __restrict__ convb) {
  int n = (blockIdx.x << 1) + (threadIdx.x >> 7);
  int b10 = (n >> 10) << 10;
  int o = (threadIdx.x & 127) << 2;
  float4 bs = *(const float4*)(bias + o);
  float a0 = bs.x, a1 = bs.y, a2 = bs.z, a3 = bs.w;
#pragma unroll
  for (int t = 0; t < 11; ++t) {
    int src = (t == 0) ? n : (b10 + adj[(size_t)n * KNB + (t - 1)]);
    const ushort* p = Y + (size_t)src * 5632 + (size_t)t * 512 + o;
    uint2 u = *(const uint2*)p;
    a0 += bf2f((ushort)(u.x & 0xffff));
    a1 += bf2f((ushort)(u.x >> 16));
    a2 += bf2f((ushort)(u.y & 0xffff));
    a3 += bf2f((ushort)(u.y >> 16));
  }
  uint2 w;
  w.x = (unsigned)f2bf(a0) | ((unsigned)f2bf(a1) << 16);
  w.y = (unsigned)f2bf(a2) | ((unsigned)f2bf(a3) << 16);
  *(uint2*)(convb + (size_t)n * 512 + o) = w;
}

// ---------------- fallback chunked gather (TC<11): accumulate f32
__global__ __launch_bounds__(256) void gather_add(const ushort* __restrict__ Y,
                                                  const int* __restrict__ adj,
                                                  float* __restrict__ convf,
                                                  int t0, int ntaps, int ncols) {
  int n = blockIdx.x;
  int b10 = (n >> 10) << 10;
  int o = threadIdx.x * 2;
  float a0 = 0.f, a1 = 0.f;
  for (int t = t0; t < t0 + ntaps; ++t) {
    int src = (t == 0) ? n : (b10 + adj[(size_t)n * KNB + (t - 1)]);
    const ushort* p = Y + (size_t)src * ncols + (size_t)(t - t0) * 512 + o;
    a0 += bf2f(p[0]);
    a1 += bf2f(p[1]);
  }
  convf[(size_t)n * 512 + o] += a0;
  convf[(size_t)n * 512 + o + 1] += a1;
}

__global__ __launch_bounds__(256) void convbias_cast(const float* __restrict__ cf,
                                                     const float* __restrict__ bias,
                                                     ushort* __restrict__ cb) {
  int i = blockIdx.x * 256 + threadIdx.x;
  float4 v = *(const float4*)(cf + (size_t)i * 4);
  int c = (i * 4) & 511;
  cb[(size_t)i * 4 + 0] = f2bf(v.x + bias[c + 0]);
  cb[(size_t)i * 4 + 1] = f2bf(v.y + bias[c + 1]);
  cb[(size_t)i * 4 + 2] = f2bf(v.z + bias[c + 2]);
  cb[(size_t)i * 4 + 3] = f2bf(v.w + bias[c + 3]);
}

// ============ gemm64: BM=64,BN=64,BK=64; 4 waves (2x2), wave 32x32 ============
__global__ __launch_bounds__(256) void gemm64(const ushort* __restrict__ A,
                                              const ushort* __restrict__ Bt,
                                              const float* __restrict__ bias,
                                              float* __restrict__ Cf,
                                              ushort* __restrict__ Cb,
                                              int Ktot) {
  __shared__ __align__(16) ushort As[2][4096];
  __shared__ __align__(16) ushort Bs[2][4096];
  int tid = threadIdx.x, w = tid >> 6, lane = tid & 63;
  int lm = lane & 15, kq = lane >> 4;
  int row0 = blockIdx.y * 64, col0 = blockIdx.x * 64;
  int wm = w >> 1, wn = w & 1;

  const ushort* gsrc[4];
  int goff[4];
  bool isA = (w < 2);
#pragma unroll
  for (int i = 0; i < 4; ++i) {
    int l = w * 4 + i, t, j;
    const ushort* base;
    if (l < 8) { t = l >> 1; j = l & 1; base = A + (size_t)(row0 + t * 16 + lm) * Ktot; }
    else { int lb = l - 8; t = lb >> 1; j = lb & 1; base = Bt + (size_t)(col0 + t * 16 + lm) * Ktot; }
    gsrc[i] = base + j * 32 + kq * 8;
    goff[i] = t * 1024 + j * 512;
  }

  floatx4 acc[2][2];
#pragma unroll
  for (int i = 0; i < 2; ++i)
#pragma unroll
    for (int j = 0; j < 2; ++j)
#pragma unroll
      for (int e = 0; e < 4; ++e) acc[i][j][e] = 0.f;

#pragma unroll
  for (int i = 0; i < 4; ++i)
    glds16(gsrc[i], (isA ? As[0] : Bs[0]) + goff[i]);

  int nsteps = Ktot >> 6;
  for (int s = 0; s < nsteps; ++s) {
    int buf = s & 1;
    __syncthreads();
    if (s + 1 < nsteps) {
      int koff = (s + 1) << 6;
      ushort* dst = (isA ? As[buf ^ 1] : Bs[buf ^ 1]);
#pragma unroll
      for (int i = 0; i < 4; ++i) glds16(gsrc[i] + koff, dst + goff[i]);
    }
#pragma unroll
    for (int j = 0; j < 2; ++j) {
      short8 a0 = *(const short8*)(&As[buf][(wm * 2 + 0) * 1024 + j * 512 + lane * 8]);
      short8 a1 = *(const short8*)(&As[buf][(wm * 2 + 1) * 1024 + j * 512 + lane * 8]);
      short8 b0 = *(const short8*)(&Bs[buf][(wn * 2 + 0) * 1024 + j * 512 + lane * 8]);
      short8 b1 = *(const short8*)(&Bs[buf][(wn * 2 + 1) * 1024 + j * 512 + lane * 8]);
      acc[0][0] = mfma16(a0, b0, acc[0][0]);
      acc[0][1] = mfma16(a0, b1, acc[0][1]);
      acc[1][0] = mfma16(a1, b0, acc[1][0]);
      acc[1][1] = mfma16(a1, b1, acc[1][1]);
    }
  }

  int colb = col0 + wn * 32;
  int rowb = row0 + wm * 32 + kq * 4;
#pragma unroll
  for (int mt = 0; mt < 2; ++mt) {
#pragma unroll
    for (int nt = 0; nt < 2; ++nt) {
      int col = colb + nt * 16 + lm;
      float bs = bias[col];
#pragma unroll
      for (int r = 0; r < 4; ++r) {
        int row = rowb + mt * 16 + r;
        float val = acc[mt][nt][r] + bs;
        size_t idx = (size_t)row * 512 + col;
        if (Cf) Cf[idx] = val;
        if (Cb) Cb[idx] = f2bf(val);
      }
    }
  }
}

// ---------------- relu+eps, /softplus(scale), focus (in-place) — k0 ONLY now
// (q-focus is fused into attn_ln_kernel, which holds full q rows per block)
__global__ __launch_bounds__(256) void focus_kernel(float* __restrict__ x,
                                                    const float* __restrict__ scale_p) {
  __shared__ float red[4];
  int row = blockIdx.x;
  float* p = x + (size_t)row * 512;
  int tid = threadIdx.x;
  float sp0 = scale_p[tid], sp1 = scale_p[tid + 256];
  float sc0 = sp0 > 20.f ? sp0 : log1pf(expf(sp0));
  float sc1 = sp1 > 20.f ? sp1 : log1pf(expf(sp1));
  float v0 = (fmaxf(p[tid], 0.f) + 1e-6f) / sc0;
  float v1 = (fmaxf(p[tid + 256], 0.f) + 1e-6f) / sc1;
  float tot = block_reduce_sum_256(v0 * v0 + v1 * v1, red);
  float n = sqrtf(tot);
  float np = n + 1e-6f;
  float f = n / (np * np * np);
  p[tid] = v0 * v0 * v0 * f;
  p[tid + 256] = v1 * v1 * v1 * f;
}

// ---------------- kv split-K x8 (256 blocks) + fused disagree-v + fused kmean
__global__ __launch_bounds__(256) void kv_kernel(const float* __restrict__ kf,
                                                 const float* __restrict__ v,
                                                 float* __restrict__ kv,
                                                 float* __restrict__ Sacc,
                                                 float* __restrict__ Dacc,
                                                 float* __restrict__ kmean) {
  __shared__ float Ks[16][64];
  __shared__ float Vs[16][64];
  __shared__ float Spart[64];
  __shared__ float Kpart[64];
  __shared__ float Dpart;
  int bh = blockIdx.x >> 3, chunk = blockIdx.x & 7;
  int b = bh >> 3, h = bh & 7;
  int tid = threadIdx.x;
  int lr = tid >> 4, lc = (tid & 15) << 2;
  int tx = tid & 15, ty = tid >> 4;
  if (tid < 64) { Spart[tid] = 0.f; Kpart[tid] = 0.f; }
  if (tid == 0) Dpart = 0.f;
  __syncthreads();
  const float* kbase = kf + (size_t)b * 524288 + h * 64 + (size_t)chunk * 128 * 512;
  const float* vbase = v + (size_t)b * 524288 + h * 64 + (size_t)chunk * 128 * 512;
  float acc[4][4] = {};
  float Sloc[4] = {0.f, 0.f, 0.f, 0.f};
  float Kloc[4] = {0.f, 0.f, 0.f, 0.f};
  float Dloc = 0.f;
  for (int n0 = 0; n0 < 128; n0 += 16) {
    float4 ke = *(const float4*)(kbase + (size_t)(n0 + lr) * 512 + lc);
    *(float4*)(&Ks[lr][lc]) = ke;
    Kloc[0] += ke.x; Kloc[1] += ke.y; Kloc[2] += ke.z; Kloc[3] += ke.w;
    float4 ve = *(const float4*)(vbase + (size_t)(n0 + lr) * 512 + lc);
    *(float4*)(&Vs[lr][lc]) = ve;
    __syncthreads();
    // disagree-v on this tile: 16-lane group reduce (threads sharing row lr)
    float sq = ve.x * ve.x + ve.y * ve.y + ve.z * ve.z + ve.w * ve.w;
#pragma unroll
    for (int m = 1; m < 16; m <<= 1) sq += __shfl_xor(sq, m, 64);
    float cn = fmaxf(sqrtf(sq), 1e-12f);
    Sloc[0] += ve.x / cn; Sloc[1] += ve.y / cn;
    Sloc[2] += ve.z / cn; Sloc[3] += ve.w / cn;
    if ((tid & 15) == 0) Dloc += sq / (cn * cn);
#pragma unroll
    for (int kk = 0; kk < 16; ++kk) {
      float a[4], bb[4];
#pragma unroll
      for (int i = 0; i < 4; ++i) a[i] = Ks[kk][ty * 4 + i];
#pragma unroll
      for (int j = 0; j < 4; ++j) bb[j] = Vs[kk][tx * 4 + j];
#pragma unroll
      for (int i = 0; i < 4; ++i)
#pragma unroll
        for (int j = 0; j < 4; ++j) acc[i][j] += a[i] * bb[j];
    }
    __syncthreads();
  }
#pragma unroll
  for (int i = 0; i < 4; ++i)
#pragma unroll
    for (int j = 0; j < 4; ++j)
      atomicAdd(&kv[(size_t)bh * 4096 + (ty * 4 + i) * 64 + tx * 4 + j],
                acc[i][j] * (1.f / 1024.f));
  // accumulate disagree-v + kmean partials: LDS then one global set
#pragma unroll
  for (int i = 0; i < 4; ++i) {
    atomicAdd(&Spart[lc + i], Sloc[i]);
    atomicAdd(&Kpart[lc + i], Kloc[i]);
  }
  if ((tid & 15) == 0) atomicAdd(&Dpart, Dloc);
  __syncthreads();
  if (tid < 64) {
    atomicAdd(&Sacc[bh * 64 + tid], Spart[tid]);
    atomicAdd(&kmean[b * 512 + h * 64 + tid], Kpart[tid] * (1.f / 1024.f));
  }
  if (tid == 64) atomicAdd(&Dacc[bh], Dpart);
}

// ---------------- fused q-focus + attn-out + z + LN + disagree-x (+disagree-kv)
// q-focus folded in: each block holds full 512-col q rows, so relu -> /softplus
// -> focus needs one extra block-reduce per row (reuses red[] + barrier pattern),
// reproducing focus_kernel's f32 math exactly. Saves the q-half of the focus
// pass and its 32MB in-place round-trip.
__global__ __launch_bounds__(512, 4) void attn_ln_kernel(const float* __restrict__ qf,
                                                         const float* __restrict__ kvf,
                                                         const float* __restrict__ kmean,
                                                         const float* __restrict__ x_local,
                                                         const float* __restrict__ scale_p,
                                                         const float* __restrict__ g,
                                                         const float* __restrict__ bp,
                                                         ushort* __restrict__ xn,
                                                         float* __restrict__ Sacc,
                                                         float* __restrict__ Dacc,
                                                         float* __restrict__ Skv,
                                                         float* __restrict__ Dkv) {
  __shared__ __align__(16) ushort kvs[32768];  // [h][dd][e] bf16, 64 KB
  __shared__ float red[16];                    // 8 sums | 8 sumsqs
  __shared__ float Sl[8][64];
  __shared__ float Dl[8];
  int r0 = blockIdx.x << 3;       // first of 8 rows
  int b = r0 >> 10;
  int c = threadIdx.x, wv = c >> 6, lane = c & 63;
  // stage kv[b] f32 -> bf16 LDS (32768 elems), coalesced float4
  const float4* kvg = (const float4*)(kvf + (size_t)b * 32768);
#pragma unroll
  for (int i = 0; i < 16; ++i) {
    float4 kvv = kvg[c + i * 512];
    int o = (c + i * 512) << 2;
    kvs[o + 0] = f2bf(kvv.x); kvs[o + 1] = f2bf(kvv.y);
    kvs[o + 2] = f2bf(kvv.z); kvs[o + 3] = f2bf(kvv.w);
  }
  float kmr = kmean[b * 512 + c];
  float gr = g[c], bpr = bp[c];
  float sp = scale_p[c];
  float sc = sp > 20.f ? sp : log1pf(expf(sp));
  float scinv = 1.f / sc;
  __syncthreads();
  // one-time: pull this thread's kv column, packed 2 bf16 per uint (32 VGPRs)
  unsigned int kvr[32];
#pragma unroll
  for (int i = 0; i < 32; ++i) {
    unsigned int lo = kvs[wv * 4096 + (2 * i) * 64 + lane];
    unsigned int hi = kvs[wv * 4096 + (2 * i + 1) * 64 + lane];
    kvr[i] = lo | (hi << 16);
  }
  float Sreg = 0.f, Dreg = 0.f;
  for (int r = 0; r < 8; ++r) {
    int row = r0 + r;
    float qraw = qf[(size_t)row * 512 + c];
    float xl = x_local[(size_t)row * 512 + c];
    // ---- fused q-focus: v0 = (relu(q)+eps)/softplus(scale); row-norm; cube
    float v0 = (fmaxf(qraw, 0.f) + 1e-6f) * scinv;
    float l2 = wave_reduce_sum(v0 * v0);
    if (lane == 0) red[wv] = l2;
    __syncthreads();
    float nq2 = red[0] + red[1] + red[2] + red[3] + red[4] + red[5] + red[6] + red[7];
    __syncthreads();
    float nq = sqrtf(nq2);
    float npq = nq + 1e-6f;
    float qv = v0 * v0 * v0 * (nq / (npq * npq * npq));
    // z = 1/(dot(q_head, kmean_head)+eps), per wave
    float zd = wave_reduce_sum(qv * kmr);
    float zz = 1.f / (zd + 1e-6f);
    // dot via readlane broadcast + packed register kv column — no LDS
    float s = 0.f;
#pragma unroll
    for (int i = 0; i < 32; ++i) {
      union { unsigned int u; float f; } lo, hi;
      lo.u = kvr[i] << 16;
      hi.u = kvr[i] & 0xffff0000u;
      s += lane_bcast(qv, 2 * i) * lo.f;
      s += lane_bcast(qv, 2 * i + 1) * hi.f;
    }
    float xv = s * zz + xl;
    // single-pass LN stats: block sum + sumsq
    float s1 = wave_reduce_sum(xv);
    float s2 = wave_reduce_sum(xv * xv);       // also the sub-vector norm^2
    if (lane == 0) { red[wv] = s1; red[8 + wv] = s2; }
    __syncthreads();
    float tsum = red[0] + red[1] + red[2] + red[3] + red[4] + red[5] + red[6] + red[7];
    float tsq = red[8] + red[9] + red[10] + red[11] + red[12] + red[13] + red[14] + red[15];
    __syncthreads();                           // red consumed before next row
    float mu = tsum * (1.f / 512.f);
    float var = tsq * (1.f / 512.f) - mu * mu;
    float inv = rsqrtf(fmaxf(var, 0.f) + 1e-5f);
    xn[(size_t)row * 512 + c] = f2bf((xv - mu) * inv * gr + bpr);
    // disagreement on x
    float norm = fmaxf(sqrtf(s2), 1e-12f);
    Sreg += xv / norm;
    Dreg += s2 / (norm * norm);
  }
  Sl[wv][lane] = Sreg;
  if (lane == 0) Dl[wv] = Dreg;
  __syncthreads();
  int gx = b * 8 + ((r0 & 1023) >> 7);
  if (c < 64) {
    float ssum = 0.f;
#pragma unroll
    for (int ww = 0; ww < 8; ++ww) ssum += Sl[ww][c];
    atomicAdd(&Sacc[gx * 64 + c], ssum);
  } else if (c == 64) {
    float dsum = 0.f;
#pragma unroll
    for (int ww = 0; ww < 8; ++ww) dsum += Dl[ww];
    atomicAdd(&Dacc[gx], dsum);
  }
  // disagree-kv: one block per batch; wave wv = head; vals from packed regs
  if ((blockIdx.x & 127) == 0) {
    float S2 = 0.f, D2 = 0.f;
#pragma unroll
    for (int i = 0; i < 32; ++i) {
      union { unsigned int u; float f; } lo, hi;
      lo.u = kvr[i] << 16;
      hi.u = kvr[i] & 0xffff0000u;
      float sq = wave_reduce_sum(lo.f * lo.f);
      float nrm = fmaxf(sqrtf(sq), 1e-12f);
      float hn = lo.f / nrm;
      S2 += hn; D2 += hn * hn;
      sq = wave_reduce_sum(hi.f * hi.f);
      nrm = fmaxf(sqrtf(sq), 1e-12f);
      hn = hi.f / nrm;
      S2 += hn; D2 += hn * hn;
    }
    float dt = wave_reduce_sum(D2);
    atomicAdd(&Skv[(b * 8 + wv) * 64 + lane], S2);
    if (lane == 0) atomicAdd(&Dkv[b * 8 + wv], dt);
  }
}

// ---------------- disagreement finals, all 3 sets in parallel (96 blocks)
__global__ __launch_bounds__(64) void disagree_final_all(const float* __restrict__ Sall,
                                                         const float* __restrict__ Dall,
                                                         float s0, float s1, float s2,
                                                         float* __restrict__ loss) {
  int set = blockIdx.x >> 5, gg = blockIdx.x & 31;
  int l = threadIdx.x;
  float sv = Sall[set * 2048 + gg * 64 + l];
  float sim = wave_reduce_sum(sv * sv);
  if (l == 0) {
    float scale = (set == 0) ? s0 : (set == 1) ? s1 : s2;
    atomicAdd(loss, (sim - Dall[set * 32 + gg]) * scale);
  }
}

extern "C" void kernel_launch(void* const* d_in, const int* in_sizes, int n_in,
                              void* d_out, int out_size, void* d_ws, size_t ws_size,
                              hipStream_t stream) {
  const float* Q       = (const float*)d_in[0];
  const int*   adj     = (const int*)d_in[1];
  const float* Wq      = (const float*)d_in[2];
  const float* bq      = (const float*)d_in[3];
  const float* Wk      = (const float*)d_in[4];
  const float* bk      = (const float*)d_in[5];
  const float* Wv      = (const float*)d_in[6];
  const float* bv      = (const float*)d_in[7];
  const float* scale_p = (const float*)d_in[8];
  const float* Wconv   = (const float*)d_in[9];
  const float* bconv   = (const float*)d_in[10];
  const float* W2      = (const float*)d_in[11];
  const float* b2      = (const float*)d_in[12];
  const float* ln_g    = (const float*)d_in[13];
  const float* ln_b    = (const float*)d_in[14];
  const float* Wo      = (const float*)d_in[15];
  const float* bo      = (const float*)d_in[16];

  float* out = (float*)d_out;
  float* loss_slot = out + MATE;

  float* ws = (float*)d_ws;
  float* q0      = ws;                 // f32; k0, v contiguous (qkv fused epilogue)
  float* k0      = q0 + MATE;
  float* v       = k0 + MATE;
  float* x_local = v + MATE;
  float* convf   = x_local + MATE;     // fallback accum only (TC<11)
  ushort* Qb    = (ushort*)(convf + MATE);
  ushort* vb    = Qb + MATE;
  ushort* convb = vb + MATE;
  ushort* xnb   = convb + MATE;
  ushort* WqT   = xnb + MATE;          // Wq|Wk|Wv transposed, contiguous (N=1536)
  ushort* W2T   = WqT + 3 * 262144;
  ushort* WoT   = W2T + 262144;
  ushort* BcY   = WoT + 262144;        // 5632 x 512 (Bt layout for Y-GEMM)
  float* biasqkv = (float*)(BcY + 5632 * 512);
  float* kmean = biasqkv + 1536;
  float* kvbuf = kmean + 2048;         // 131072 (zeroed)
  float* Sv    = kvbuf + 131072;       // Sv|Skv|Sx contiguous
  float* Skv   = Sv + 2048;
  float* Sx    = Skv + 2048;
  float* Dv    = Sx + 2048;            // Dv|Dkv|Dx contiguous
  float* Dkv   = Dv + 32;
  float* Dx    = Dkv + 32;
  float* ytail = Dx + 32;
  ushort* Ybf  = (ushort*)ytail;       // Y buffer: TC taps x 4096 x 512 bf16

  size_t used_floats = (size_t)(ytail - ws);
  size_t avail_floats = (ws_size / 4 > used_floats) ? (ws_size / 4 - used_floats) : 0;
  int TC = (int)(avail_floats / (MATE / 2));
  if (TC < 1) TC = 1;
  if (TC > 11) TC = 11;

  // all one-time repacks + accumulator zeroing in one launch (memsets folded)
  prep_kernel<<<4490, 256, 0, stream>>>(Wq, Wk, Wv, W2, Wo, Wconv, Q,
                                        bq, bk, bv, WqT, BcY, biasqkv, Qb,
                                        kmean, loss_slot);

  // fused q,k,v: 128x128 tile BK=32, N=1536, grid 12x32 = 384 blocks
  gemm128_qkv<<<dim3(12, 32), 256, 0, stream>>>(Qb, WqT, biasqkv, q0, vb);

  // conv: Y = vb @ Wcat (M=4096, N=5632, K=512), then gather(+bias) -> convb
  if (TC >= 11) {
    gemm128<<<dim3(44, 32), 256, 0, stream>>>(vb, BcY, Ybf, 512, 5632);
    gather_add_bias<<<2048, 256, 0, stream>>>(Ybf, adj, bconv, convb);
  } else {
    hipMemsetAsync(convf, 0, MATE * sizeof(float), stream);
    for (int t0 = 0; t0 < 11; t0 += TC) {
      int nt = (11 - t0 < TC) ? (11 - t0) : TC;
      int ncols = nt * 512;
      gemm128<<<dim3(ncols / 128, 32), 256, 0, stream>>>(
          vb, BcY + (size_t)(t0 * 512) * 512, Ybf, 512, ncols);
      gather_add<<<4096, 256, 0, stream>>>(Ybf, adj, convf, t0, nt, ncols);
    }
    convbias_cast<<<2048, 256, 0, stream>>>(convf, bconv, convb);
  }

  gemm64<<<dim3(8, 64), 256, 0, stream>>>(convb, W2T, b2, x_local, nullptr, 512);

  // focus on k0 only (q-focus fused into attn_ln)
  focus_kernel<<<TOK_TOTAL, 256, 0, stream>>>(k0, scale_p);

  // kv + fused disagree-v + fused kmean
  kv_kernel<<<256, 256, 0, stream>>>(k0, v, kvbuf, Sv, Dv, kmean);

  // fused q-focus + attention-out + z + LayerNorm + disagree-x + disagree-kv
  attn_ln_kernel<<<512, 512, 0, stream>>>(q0, kvbuf, kmean, x_local, scale_p,
                                          ln_g, ln_b, xnb, Sx, Dx, Skv, Dkv);

  disagree_final_all<<<96, 64, 0, stream>>>(Sv, Dv,
                                            1.f / (33554432.f * 3.f),
                                            1.f / (131072.f * 3.f),
                                            1.f / (33554432.f * 3.f), loss_slot);

  gemm64<<<dim3(8, 64), 256, 0, stream>>>(xnb, WoT, bo, out, nullptr, 512);
}

// Round 13
// 285.824 us; speedup vs baseline: 1.1645x; 1.0080x over previous
//
#include <hip/hip_runtime.h>
#include <math.h>

// Problem constants: B=4, N=1024, C=512, K=10, H=8, d=64
#define TOK_TOTAL 4096          // B*N
#define KNB 10
#define MATE 2097152            // 4096*512 elements

typedef __attribute__((ext_vector_type(8))) short short8;
typedef __attribute__((ext_vector_type(4))) float floatx4;
typedef unsigned short ushort;

__device__ __forceinline__ floatx4 mfma16(short8 a, short8 b, floatx4 c) {
  return __builtin_amdgcn_mfma_f32_16x16x32_bf16(a, b, c, 0, 0, 0);
}

__device__ __forceinline__ ushort f2bf(float f) {
  union { float f; unsigned int u; } x; x.f = f;
  unsigned int r = x.u + 0x7fffu + ((x.u >> 16) & 1u);
  return (ushort)(r >> 16);
}

__device__ __forceinline__ float bf2f(ushort u) {
  union { unsigned int u; float f; } x; x.u = ((unsigned int)u) << 16;
  return x.f;
}

__device__ __forceinline__ float lane_bcast(float v, int l) {
  union { float f; int i; } x; x.f = v;
  x.i = __builtin_amdgcn_readlane(x.i, l);
  return x.f;
}

// async global->LDS DMA, 16B/lane; LDS dest = wave-uniform base + lane*16
__device__ __forceinline__ void glds16(const ushort* g, ushort* l) {
  __builtin_amdgcn_global_load_lds((const __attribute__((address_space(1))) void*)g,
                                   (__attribute__((address_space(3))) void*)l, 16, 0, 0);
}

__device__ __forceinline__ float wave_reduce_sum(float v) {
#pragma unroll
  for (int m = 32; m >= 1; m >>= 1) v += __shfl_xor(v, m, 64);
  return v;
}

__device__ __forceinline__ float block_reduce_sum_256(float v, float* red) {
  v = wave_reduce_sum(v);
  __syncthreads();
  if ((threadIdx.x & 63) == 0) red[threadIdx.x >> 6] = v;
  __syncthreads();
  return red[0] + red[1] + red[2] + red[3];
}

// ---------------- one prep kernel: 5 weight transposes | wconv repack | bias pack |
// Q cast | accumulator-zeroing (folds the two hipMemsetAsync dispatches)
__global__ __launch_bounds__(256) void prep_kernel(const float* __restrict__ Wq,
                                                   const float* __restrict__ Wk,
                                                   const float* __restrict__ Wv,
                                                   const float* __restrict__ W2p,
                                                   const float* __restrict__ Wo,
                                                   const float* __restrict__ Wconv,
                                                   const float* __restrict__ Q,
                                                   const float* __restrict__ bq,
                                                   const float* __restrict__ bk,
                                                   const float* __restrict__ bv,
                                                   ushort* __restrict__ WT,   // 5x512x512
                                                   ushort* __restrict__ BcY,  // 5632x512
                                                   float* __restrict__ biasqkv,
                                                   ushort* __restrict__ Qb,
                                                   float* __restrict__ zbase, // kmean..Dx, 139360 f
                                                   float* __restrict__ loss) {
  int blk = blockIdx.x;
  if (blk < 1280) {
    __shared__ float tile[32][33];
    int zz = blk >> 8, rem = blk & 255;
    const float* W = (zz == 0) ? Wq : (zz == 1) ? Wk : (zz == 2) ? Wv
                     : (zz == 3) ? W2p : Wo;
    ushort* Wt = WT + (size_t)zz * 262144;
    int n0 = (rem & 15) * 32, k0 = (rem >> 4) * 32;
    int tx = threadIdx.x & 31, ty = threadIdx.x >> 5;  // 32 x 8
#pragma unroll
    for (int i = 0; i < 32; i += 8)
      tile[ty + i][tx] = W[(size_t)(k0 + ty + i) * 512 + n0 + tx];
    __syncthreads();
#pragma unroll
    for (int i = 0; i < 32; i += 8)
      Wt[(size_t)(n0 + ty + i) * 512 + k0 + tx] = f2bf(tile[tx][ty + i]);
  } else if (blk < 2304) {
    int i = (blk - 1280) * 256 + threadIdx.x;  // o*512+c
    const float* src = Wconv + (size_t)i * 11;
    int o = i >> 9, c = i & 511;
#pragma unroll
    for (int t = 0; t < 11; ++t)
      BcY[(((size_t)(t * 512 + o)) << 9) + c] = f2bf(src[t]);
  } else if (blk == 2304) {
    for (int i = threadIdx.x; i < 1536; i += 256)
      biasqkv[i] = (i < 512) ? bq[i] : ((i < 1024) ? bk[i - 512] : bv[i - 1024]);
  } else if (blk < 4353) {
    int i = (blk - 2305) * 256 + threadIdx.x;  // x4 floats
    float4 v = *(const float4*)(Q + (size_t)i * 4);
    Qb[(size_t)i * 4 + 0] = f2bf(v.x);
    Qb[(size_t)i * 4 + 1] = f2bf(v.y);
    Qb[(size_t)i * 4 + 2] = f2bf(v.z);
    Qb[(size_t)i * 4 + 3] = f2bf(v.w);
  } else {
    // zero kmean|kvbuf|Sv|Skv|Sx|Dv|Dkv|Dx (139360 floats = 34840 float4)
    int i = (blk - 4353) * 256 + threadIdx.x;
    if (i < 34840) {
      float4 z; z.x = 0.f; z.y = 0.f; z.z = 0.f; z.w = 0.f;
      ((float4*)zbase)[i] = z;
    }
    if (blk == 4353 && threadIdx.x == 0) loss[0] = 0.f;
  }
}

// ============ gemm_conv v7: BM=256, BN=128, BK=32; 512 thr = 8 waves (4x2),
// wave 64x64 (unchanged fragment<->lane mapping). Steady-state schedule is
// pinned (R0/R4/R6/R9/R10: six variants all ~55us); the remaining cost is
// SHORT-K amortization -- at K=512 each block pays prologue+epilogue+ramp over
// just 16 steps (we run ~3050 cyc/32KB-step vs m97's ~1470 at K=4096). BM=256
// doubles output per block: staging/output -25%, blocks halve (704) -> half the
// ramp overhead. 24 slabs x 512 elems per buffer; wave w stages slabs 3w..3w+2.
// Proven 2-buffer __syncthreads double-buffer schedule (R4). LDS 48KB, 2 blk/CU.
__global__ __launch_bounds__(512, 4) void gemm_conv(const ushort* __restrict__ A,
                                                    const ushort* __restrict__ Bt,
                                                    ushort* __restrict__ Cb,
                                                    int Ktot, int Ncols) {
  __shared__ __align__(16) ushort SS[2][12288];  // 24 slabs x 512 (A 0..15, B 16..23)
  int tid = threadIdx.x, w = tid >> 6, lane = tid & 63;
  int lm = lane & 15, kq = lane >> 4;
  int row0 = blockIdx.y * 256, col0 = blockIdx.x * 128;
  int wm = w >> 1, wn = w & 1;   // 4x2 wave grid over 256x128

  const ushort* gs[3];
  int go[3];
#pragma unroll
  for (int i = 0; i < 3; ++i) {
    int slab = 3 * w + i;
    const ushort* base = (slab < 16)
        ? (A + (size_t)(row0 + slab * 16 + lm) * Ktot)
        : (Bt + (size_t)(col0 + (slab - 16) * 16 + lm) * Ktot);
    gs[i] = base + kq * 8;
    go[i] = slab * 512;
  }

  floatx4 acc[4][4];
#pragma unroll
  for (int i = 0; i < 4; ++i)
#pragma unroll
    for (int j = 0; j < 4; ++j)
#pragma unroll
      for (int e = 0; e < 4; ++e) acc[i][j][e] = 0.f;

#pragma unroll
  for (int i = 0; i < 3; ++i) glds16(gs[i], SS[0] + go[i]);

  int nsteps = Ktot >> 5;  // K=512 -> 16
  for (int s = 0; s < nsteps; ++s) {
    int buf = s & 1;
    __syncthreads();
    if (s + 1 < nsteps) {
      int koff = (s + 1) << 5;
      ushort* dst = SS[buf ^ 1];
#pragma unroll
      for (int i = 0; i < 3; ++i) glds16(gs[i] + koff, dst + go[i]);
    }
    short8 a[4], b[4];
#pragma unroll
    for (int mt = 0; mt < 4; ++mt)
      a[mt] = *(const short8*)(&SS[buf][(wm * 4 + mt) * 512 + lane * 8]);
#pragma unroll
    for (int nt = 0; nt < 4; ++nt)
      b[nt] = *(const short8*)(&SS[buf][8192 + (wn * 4 + nt) * 512 + lane * 8]);
#pragma unroll
    for (int mt = 0; mt < 4; ++mt)
#pragma unroll
      for (int nt = 0; nt < 4; ++nt)
        acc[mt][nt] = mfma16(a[mt], b[nt], acc[mt][nt]);
  }

#pragma unroll
  for (int mt = 0; mt < 4; ++mt) {
#pragma unroll
    for (int nt = 0; nt < 4; ++nt) {
      int col = col0 + wn * 64 + nt * 16 + lm;
#pragma unroll
      for (int r = 0; r < 4; ++r) {
        int row = row0 + wm * 64 + mt * 16 + kq * 4 + r;
        Cb[(size_t)row * Ncols + col] = f2bf(acc[mt][nt][r]);
      }
    }
  }
}

// ============ gemm128_qkv v3 (proven, R4): BK=32, N=1536 fixed, K=512 (16 steps)
__global__ __launch_bounds__(256, 4) void gemm128_qkv(const ushort* __restrict__ A,
                                                      const ushort* __restrict__ Bt,
                                                      const float* __restrict__ bias,
                                                      float* __restrict__ outf,
                                                      ushort* __restrict__ vb) {
  __shared__ __align__(16) ushort As[2][4096];
  __shared__ __align__(16) ushort Bs[2][4096];
  int tid = threadIdx.x, w = tid >> 6, lane = tid & 63;
  int lm = lane & 15, kq = lane >> 4;
  int row0 = blockIdx.y * 128, col0 = blockIdx.x * 128;
  int wm = w >> 1, wn = w & 1;

  bool isA = (w < 2);
  const ushort* gs[4];
  int go[4];
#pragma unroll
  for (int i = 0; i < 4; ++i) {
    int slab = (w & 1) * 4 + i;
    const ushort* base = isA ? (A + (size_t)(row0 + slab * 16 + lm) * 512)
                             : (Bt + (size_t)(col0 + slab * 16 + lm) * 512);
    gs[i] = base + kq * 8;
    go[i] = slab * 512;
  }

  floatx4 acc[4][4];
#pragma unroll
  for (int i = 0; i < 4; ++i)
#pragma unroll
    for (int j = 0; j < 4; ++j)
#pragma unroll
      for (int e = 0; e < 4; ++e) acc[i][j][e] = 0.f;

#pragma unroll
  for (int i = 0; i < 4; ++i)
    glds16(gs[i], (isA ? As[0] : Bs[0]) + go[i]);

  for (int s = 0; s < 16; ++s) {
    int buf = s & 1;
    __syncthreads();
    if (s + 1 < 16) {
      int koff = (s + 1) << 5;
      ushort* dst = (isA ? As[buf ^ 1] : Bs[buf ^ 1]);
#pragma unroll
      for (int i = 0; i < 4; ++i) glds16(gs[i] + koff, dst + go[i]);
    }
    short8 a[4], b[4];
#pragma unroll
    for (int mt = 0; mt < 4; ++mt)
      a[mt] = *(const short8*)(&As[buf][(wm * 4 + mt) * 512 + lane * 8]);
#pragma unroll
    for (int nt = 0; nt < 4; ++nt)
      b[nt] = *(const short8*)(&Bs[buf][(wn * 4 + nt) * 512 + lane * 8]);
#pragma unroll
    for (int mt = 0; mt < 4; ++mt)
#pragma unroll
      for (int nt = 0; nt < 4; ++nt)
        acc[mt][nt] = mfma16(a[mt], b[nt], acc[mt][nt]);
  }

#pragma unroll
  for (int mt = 0; mt < 4; ++mt) {
#pragma unroll
    for (int nt = 0; nt < 4; ++nt) {
      int col = col0 + wn * 64 + nt * 16 + lm;  // 0..1535
      int mat = col >> 9, cc = col & 511;
      float bs = bias[col];
#pragma unroll
      for (int r = 0; r < 4; ++r) {
        int row = row0 + wm * 64 + mt * 16 + kq * 4 + r;
        float val = acc[mt][nt][r] + bs;
        size_t idx = (size_t)row * 512 + cc;
        outf[(size_t)mat * MATE + idx] = val;
        if (mat == 2) vb[idx] = f2bf(val);
      }
    }
  }
}

// ---------------- conv gather: 2 rows/block, uint2 (4 bf16) per thread
__global__ __launch_bounds__(256) void gather_add_bias(const ushort* __restrict__ Y,
                                                       const int* __restrict__ adj,
                                                       const float* __restrict__ bias,
                                                       ushort* __restrict__ convb) {
  int n = (blockIdx.x << 1) + (threadIdx.x >> 7);
  int b10 = (n >> 10) << 10;
  int o = (threadIdx.x & 127) << 2;
  float4 bs = *(const float4*)(bias + o);
  float a0 = bs.x, a1 = bs.y, a2 = bs.z, a3 = bs.w;
#pragma unroll
  for (int t = 0; t < 11; ++t) {
    int src = (t == 0) ? n : (b10 + adj[(size_t)n * KNB + (t - 1)]);
    const ushort* p = Y + (size_t)src * 5632 + (size_t)t * 512 + o;
    uint2 u = *(const uint2*)p;
    a0 += bf2f((ushort)(u.x & 0xffff));
    a1 += bf2f((ushort)(u.x >> 16));
    a2 += bf2f((ushort)(u.y & 0xffff));
    a3 += bf2f((ushort)(u.y >> 16));
  }
  uint2 w;
  w.x = (unsigned)f2bf(a0) | ((unsigned)f2bf(a1) << 16);
  w.y = (unsigned)f2bf(a2) | ((unsigned)f2bf(a3) << 16);
  *(uint2*)(convb + (size_t)n * 512 + o) = w;
}

// ---------------- fallback chunked gather (TC<11): accumulate f32
__global__ __launch_bounds__(256) void gather_add(const ushort* __restrict__ Y,
                                                  const int* __restrict__ adj,
                                                  float* __restrict__ convf,
                                                  int t0, int ntaps, int ncols) {
  int n = blockIdx.x;
  int b10 = (n >> 10) << 10;
  int o = threadIdx.x * 2;
  float a0 = 0.f, a1 = 0.f;
  for (int t = t0; t < t0 + ntaps; ++t) {
    int src = (t == 0) ? n : (b10 + adj[(size_t)n * KNB + (t - 1)]);
    const ushort* p = Y + (size_t)src * ncols + (size_t)(t - t0) * 512 + o;
    a0 += bf2f(p[0]);
    a1 += bf2f(p[1]);
  }
  convf[(size_t)n * 512 + o] += a0;
  convf[(size_t)n * 512 + o + 1] += a1;
}

__global__ __launch_bounds__(256) void convbias_cast(const float* __restrict__ cf,
                                                     const float* __restrict__ bias,
                                                     ushort* __restrict__ cb) {
  int i = blockIdx.x * 256 + threadIdx.x;
  float4 v = *(const float4*)(cf + (size_t)i * 4);
  int c = (i * 4) & 511;
  cb[(size_t)i * 4 + 0] = f2bf(v.x + bias[c + 0]);
  cb[(size_t)i * 4 + 1] = f2bf(v.y + bias[c + 1]);
  cb[(size_t)i * 4 + 2] = f2bf(v.z + bias[c + 2]);
  cb[(size_t)i * 4 + 3] = f2bf(v.w + bias[c + 3]);
}

// ============ gemm64: BM=64,BN=64,BK=64; 4 waves (2x2), wave 32x32 ============
__global__ __launch_bounds__(256) void gemm64(const ushort* __restrict__ A,
                                              const ushort* __restrict__ Bt,
                                              const float* __restrict__ bias,
                                              float* __restrict__ Cf,
                                              ushort* __restrict__ Cb,
                                              int Ktot) {
  __shared__ __align__(16) ushort As[2][4096];
  __shared__ __align__(16) ushort Bs[2][4096];
  int tid = threadIdx.x, w = tid >> 6, lane = tid & 63;
  int lm = lane & 15, kq = lane >> 4;
  int row0 = blockIdx.y * 64, col0 = blockIdx.x * 64;
  int wm = w >> 1, wn = w & 1;

  const ushort* gsrc[4];
  int goff[4];
  bool isA = (w < 2);
#pragma unroll
  for (int i = 0; i < 4; ++i) {
    int l = w * 4 + i, t, j;
    const ushort* base;
    if (l < 8) { t = l >> 1; j = l & 1; base = A + (size_t)(row0 + t * 16 + lm) * Ktot; }
    else { int lb = l - 8; t = lb >> 1; j = lb & 1; base = Bt + (size_t)(col0 + t * 16 + lm) * Ktot; }
    gsrc[i] = base + j * 32 + kq * 8;
    goff[i] = t * 1024 + j * 512;
  }

  floatx4 acc[2][2];
#pragma unroll
  for (int i = 0; i < 2; ++i)
#pragma unroll
    for (int j = 0; j < 2; ++j)
#pragma unroll
      for (int e = 0; e < 4; ++e) acc[i][j][e] = 0.f;

#pragma unroll
  for (int i = 0; i < 4; ++i)
    glds16(gsrc[i], (isA ? As[0] : Bs[0]) + goff[i]);

  int nsteps = Ktot >> 6;
  for (int s = 0; s < nsteps; ++s) {
    int buf = s & 1;
    __syncthreads();
    if (s + 1 < nsteps) {
      int koff = (s + 1) << 6;
      ushort* dst = (isA ? As[buf ^ 1] : Bs[buf ^ 1]);
#pragma unroll
      for (int i = 0; i < 4; ++i) glds16(gsrc[i] + koff, dst + goff[i]);
    }
#pragma unroll
    for (int j = 0; j < 2; ++j) {
      short8 a0 = *(const short8*)(&As[buf][(wm * 2 + 0) * 1024 + j * 512 + lane * 8]);
      short8 a1 = *(const short8*)(&As[buf][(wm * 2 + 1) * 1024 + j * 512 + lane * 8]);
      short8 b0 = *(const short8*)(&Bs[buf][(wn * 2 + 0) * 1024 + j * 512 + lane * 8]);
      short8 b1 = *(const short8*)(&Bs[buf][(wn * 2 + 1) * 1024 + j * 512 + lane * 8]);
      acc[0][0] = mfma16(a0, b0, acc[0][0]);
      acc[0][1] = mfma16(a0, b1, acc[0][1]);
      acc[1][0] = mfma16(a1, b0, acc[1][0]);
      acc[1][1] = mfma16(a1, b1, acc[1][1]);
    }
  }

  int colb = col0 + wn * 32;
  int rowb = row0 + wm * 32 + kq * 4;
#pragma unroll
  for (int mt = 0; mt < 2; ++mt) {
#pragma unroll
    for (int nt = 0; nt < 2; ++nt) {
      int col = colb + nt * 16 + lm;
      float bs = bias[col];
#pragma unroll
      for (int r = 0; r < 4; ++r) {
        int row = rowb + mt * 16 + r;
        float val = acc[mt][nt][r] + bs;
        size_t idx = (size_t)row * 512 + col;
        if (Cf) Cf[idx] = val;
        if (Cb) Cb[idx] = f2bf(val);
      }
    }
  }
}

// ---------------- relu+eps, /softplus(scale), focus (in-place) — k0 ONLY
__global__ __launch_bounds__(256) void focus_kernel(float* __restrict__ x,
                                                    const float* __restrict__ scale_p) {
  __shared__ float red[4];
  int row = blockIdx.x;
  float* p = x + (size_t)row * 512;
  int tid = threadIdx.x;
  float sp0 = scale_p[tid], sp1 = scale_p[tid + 256];
  float sc0 = sp0 > 20.f ? sp0 : log1pf(expf(sp0));
  float sc1 = sp1 > 20.f ? sp1 : log1pf(expf(sp1));
  float v0 = (fmaxf(p[tid], 0.f) + 1e-6f) / sc0;
  float v1 = (fmaxf(p[tid + 256], 0.f) + 1e-6f) / sc1;
  float tot = block_reduce_sum_256(v0 * v0 + v1 * v1, red);
  float n = sqrtf(tot);
  float np = n + 1e-6f;
  float f = n / (np * np * np);
  p[tid] = v0 * v0 * v0 * f;
  p[tid + 256] = v1 * v1 * v1 * f;
}

// ---------------- kv split-K x8 (256 blocks) + fused disagree-v + fused kmean
__global__ __launch_bounds__(256) void kv_kernel(const float* __restrict__ kf,
                                                 const float* __restrict__ v,
                                                 float* __restrict__ kv,
                                                 float* __restrict__ Sacc,
                                                 float* __restrict__ Dacc,
                                                 float* __restrict__ kmean) {
  __shared__ float Ks[16][64];
  __shared__ float Vs[16][64];
  __shared__ float Spart[64];
  __shared__ float Kpart[64];
  __shared__ float Dpart;
  int bh = blockIdx.x >> 3, chunk = blockIdx.x & 7;
  int b = bh >> 3, h = bh & 7;
  int tid = threadIdx.x;
  int lr = tid >> 4, lc = (tid & 15) << 2;
  int tx = tid & 15, ty = tid >> 4;
  if (tid < 64) { Spart[tid] = 0.f; Kpart[tid] = 0.f; }
  if (tid == 0) Dpart = 0.f;
  __syncthreads();
  const float* kbase = kf + (size_t)b * 524288 + h * 64 + (size_t)chunk * 128 * 512;
  const float* vbase = v + (size_t)b * 524288 + h * 64 + (size_t)chunk * 128 * 512;
  float acc[4][4] = {};
  float Sloc[4] = {0.f, 0.f, 0.f, 0.f};
  float Kloc[4] = {0.f, 0.f, 0.f, 0.f};
  float Dloc = 0.f;
  for (int n0 = 0; n0 < 128; n0 += 16) {
    float4 ke = *(const float4*)(kbase + (size_t)(n0 + lr) * 512 + lc);
    *(float4*)(&Ks[lr][lc]) = ke;
    Kloc[0] += ke.x; Kloc[1] += ke.y; Kloc[2] += ke.z; Kloc[3] += ke.w;
    float4 ve = *(const float4*)(vbase + (size_t)(n0 + lr) * 512 + lc);
    *(float4*)(&Vs[lr][lc]) = ve;
    __syncthreads();
    // disagree-v on this tile: 16-lane group reduce (threads sharing row lr)
    float sq = ve.x * ve.x + ve.y * ve.y + ve.z * ve.z + ve.w * ve.w;
#pragma unroll
    for (int m = 1; m < 16; m <<= 1) sq += __shfl_xor(sq, m, 64);
    float cn = fmaxf(sqrtf(sq), 1e-12f);
    Sloc[0] += ve.x / cn; Sloc[1] += ve.y / cn;
    Sloc[2] += ve.z / cn; Sloc[3] += ve.w / cn;
    if ((tid & 15) == 0) Dloc += sq / (cn * cn);
#pragma unroll
    for (int kk = 0; kk < 16; ++kk) {
      float a[4], bb[4];
#pragma unroll
      for (int i = 0; i < 4; ++i) a[i] = Ks[kk][ty * 4 + i];
#pragma unroll
      for (int j = 0; j < 4; ++j) bb[j] = Vs[kk][tx * 4 + j];
#pragma unroll
      for (int i = 0; i < 4; ++i)
#pragma unroll
        for (int j = 0; j < 4; ++j) acc[i][j] += a[i] * bb[j];
    }
    __syncthreads();
  }
#pragma unroll
  for (int i = 0; i < 4; ++i)
#pragma unroll
    for (int j = 0; j < 4; ++j)
      atomicAdd(&kv[(size_t)bh * 4096 + (ty * 4 + i) * 64 + tx * 4 + j],
                acc[i][j] * (1.f / 1024.f));
  // accumulate disagree-v + kmean partials: LDS then one global set
#pragma unroll
  for (int i = 0; i < 4; ++i) {
    atomicAdd(&Spart[lc + i], Sloc[i]);
    atomicAdd(&Kpart[lc + i], Kloc[i]);
  }
  if ((tid & 15) == 0) atomicAdd(&Dpart, Dloc);
  __syncthreads();
  if (tid < 64) {
    atomicAdd(&Sacc[bh * 64 + tid], Spart[tid]);
    atomicAdd(&kmean[b * 512 + h * 64 + tid], Kpart[tid] * (1.f / 1024.f));
  }
  if (tid == 64) atomicAdd(&Dacc[bh], Dpart);
}

// ---------------- fused q-focus + attn-out + z + LN + disagree-x (+disagree-kv)
__global__ __launch_bounds__(512, 4) void attn_ln_kernel(const float* __restrict__ qf,
                                                         const float* __restrict__ kvf,
                                                         const float* __restrict__ kmean,
                                                         const float* __restrict__ x_local,
                                                         const float* __restrict__ scale_p,
                                                         const float* __restrict__ g,
                                                         const float* __restrict__ bp,
                                                         ushort* __restrict__ xn,
                                                         float* __restrict__ Sacc,
                                                         float* __restrict__ Dacc,
                                                         float* __restrict__ Skv,
                                                         float* __restrict__ Dkv) {
  __shared__ __align__(16) ushort kvs[32768];  // [h][dd][e] bf16, 64 KB
  __shared__ float red[16];                    // 8 sums | 8 sumsqs
  __shared__ float Sl[8][64];
  __shared__ float Dl[8];
  int r0 = blockIdx.x << 3;       // first of 8 rows
  int b = r0 >> 10;
  int c = threadIdx.x, wv = c >> 6, lane = c & 63;
  // stage kv[b] f32 -> bf16 LDS (32768 elems), coalesced float4
  const float4* kvg = (const float4*)(kvf + (size_t)b * 32768);
#pragma unroll
  for (int i = 0; i < 16; ++i) {
    float4 kvv = kvg[c + i * 512];
    int o = (c + i * 512) << 2;
    kvs[o + 0] = f2bf(kvv.x); kvs[o + 1] = f2bf(kvv.y);
    kvs[o + 2] = f2bf(kvv.z); kvs[o + 3] = f2bf(kvv.w);
  }
  float kmr = kmean[b * 512 + c];
  float gr = g[c], bpr = bp[c];
  float sp = scale_p[c];
  float sc = sp > 20.f ? sp : log1pf(expf(sp));
  float scinv = 1.f / sc;
  __syncthreads();
  // one-time: pull this thread's kv column, packed 2 bf16 per uint (32 VGPRs)
  unsigned int kvr[32];
#pragma unroll
  for (int i = 0; i < 32; ++i) {
    unsigned int lo = kvs[wv * 4096 + (2 * i) * 64 + lane];
    unsigned int hi = kvs[wv * 4096 + (2 * i + 1) * 64 + lane];
    kvr[i] = lo | (hi << 16);
  }
  float Sreg = 0.f, Dreg = 0.f;
  for (int r = 0; r < 8; ++r) {
    int row = r0 + r;
    float qraw = qf[(size_t)row * 512 + c];
    float xl = x_local[(size_t)row * 512 + c];
    // ---- fused q-focus: v0 = (relu(q)+eps)/softplus(scale); row-norm; cube
    float v0 = (fmaxf(qraw, 0.f) + 1e-6f) * scinv;
    float l2 = wave_reduce_sum(v0 * v0);
    if (lane == 0) red[wv] = l2;
    __syncthreads();
    float nq2 = red[0] + red[1] + red[2] + red[3] + red[4] + red[5] + red[6] + red[7];
    __syncthreads();
    float nq = sqrtf(nq2);
    float npq = nq + 1e-6f;
    float qv = v0 * v0 * v0 * (nq / (npq * npq * npq));
    // z = 1/(dot(q_head, kmean_head)+eps), per wave
    float zd = wave_reduce_sum(qv * kmr);
    float zz = 1.f / (zd + 1e-6f);
    // dot via readlane broadcast + packed register kv column — no LDS
    float s = 0.f;
#pragma unroll
    for (int i = 0; i < 32; ++i) {
      union { unsigned int u; float f; } lo, hi;
      lo.u = kvr[i] << 16;
      hi.u = kvr[i] & 0xffff0000u;
      s += lane_bcast(qv, 2 * i) * lo.f;
      s += lane_bcast(qv, 2 * i + 1) * hi.f;
    }
    float xv = s * zz + xl;
    // single-pass LN stats: block sum + sumsq
    float s1 = wave_reduce_sum(xv);
    float s2 = wave_reduce_sum(xv * xv);       // also the sub-vector norm^2
    if (lane == 0) { red[wv] = s1; red[8 + wv] = s2; }
    __syncthreads();
    float tsum = red[0] + red[1] + red[2] + red[3] + red[4] + red[5] + red[6] + red[7];
    float tsq = red[8] + red[9] + red[10] + red[11] + red[12] + red[13] + red[14] + red[15];
    __syncthreads();                           // red consumed before next row
    float mu = tsum * (1.f / 512.f);
    float var = tsq * (1.f / 512.f) - mu * mu;
    float inv = rsqrtf(fmaxf(var, 0.f) + 1e-5f);
    xn[(size_t)row * 512 + c] = f2bf((xv - mu) * inv * gr + bpr);
    // disagreement on x
    float norm = fmaxf(sqrtf(s2), 1e-12f);
    Sreg += xv / norm;
    Dreg += s2 / (norm * norm);
  }
  Sl[wv][lane] = Sreg;
  if (lane == 0) Dl[wv] = Dreg;
  __syncthreads();
  int gx = b * 8 + ((r0 & 1023) >> 7);
  if (c < 64) {
    float ssum = 0.f;
#pragma unroll
    for (int ww = 0; ww < 8; ++ww) ssum += Sl[ww][c];
    atomicAdd(&Sacc[gx * 64 + c], ssum);
  } else if (c == 64) {
    float dsum = 0.f;
#pragma unroll
    for (int ww = 0; ww < 8; ++ww) dsum += Dl[ww];
    atomicAdd(&Dacc[gx], dsum);
  }
  // disagree-kv: one block per batch; wave wv = head; vals from packed regs
  if ((blockIdx.x & 127) == 0) {
    float S2 = 0.f, D2 = 0.f;
#pragma unroll
    for (int i = 0; i < 32; ++i) {
      union { unsigned int u; float f; } lo, hi;
      lo.u = kvr[i] << 16;
      hi.u = kvr[i] & 0xffff0000u;
      float sq = wave_reduce_sum(lo.f * lo.f);
      float nrm = fmaxf(sqrtf(sq), 1e-12f);
      float hn = lo.f / nrm;
      S2 += hn; D2 += hn * hn;
      sq = wave_reduce_sum(hi.f * hi.f);
      nrm = fmaxf(sqrtf(sq), 1e-12f);
      hn = hi.f / nrm;
      S2 += hn; D2 += hn * hn;
    }
    float dt = wave_reduce_sum(D2);
    atomicAdd(&Skv[(b * 8 + wv) * 64 + lane], S2);
    if (lane == 0) atomicAdd(&Dkv[b * 8 + wv], dt);
  }
}

// ---------------- disagreement finals, all 3 sets in parallel (96 blocks)
__global__ __launch_bounds__(64) void disagree_final_all(const float* __restrict__ Sall,
                                                         const float* __restrict__ Dall,
                                                         float s0, float s1, float s2,
                                                         float* __restrict__ loss) {
  int set = blockIdx.x >> 5, gg = blockIdx.x & 31;
  int l = threadIdx.x;
  float sv = Sall[set * 2048 + gg * 64 + l];
  float sim = wave_reduce_sum(sv * sv);
  if (l == 0) {
    float scale = (set == 0) ? s0 : (set == 1) ? s1 : s2;
    atomicAdd(loss, (sim - Dall[set * 32 + gg]) * scale);
  }
}

extern "C" void kernel_launch(void* const* d_in, const int* in_sizes, int n_in,
                              void* d_out, int out_size, void* d_ws, size_t ws_size,
                              hipStream_t stream) {
  const float* Q       = (const float*)d_in[0];
  const int*   adj     = (const int*)d_in[1];
  const float* Wq      = (const float*)d_in[2];
  const float* bq      = (const float*)d_in[3];
  const float* Wk      = (const float*)d_in[4];
  const float* bk      = (const float*)d_in[5];
  const float* Wv      = (const float*)d_in[6];
  const float* bv      = (const float*)d_in[7];
  const float* scale_p = (const float*)d_in[8];
  const float* Wconv   = (const float*)d_in[9];
  const float* bconv   = (const float*)d_in[10];
  const float* W2      = (const float*)d_in[11];
  const float* b2      = (const float*)d_in[12];
  const float* ln_g    = (const float*)d_in[13];
  const float* ln_b    = (const float*)d_in[14];
  const float* Wo      = (const float*)d_in[15];
  const float* bo      = (const float*)d_in[16];

  float* out = (float*)d_out;
  float* loss_slot = out + MATE;

  float* ws = (float*)d_ws;
  float* q0      = ws;                 // f32; k0, v contiguous (qkv fused epilogue)
  float* k0      = q0 + MATE;
  float* v       = k0 + MATE;
  float* x_local = v + MATE;
  float* convf   = x_local + MATE;     // fallback accum only (TC<11)
  ushort* Qb    = (ushort*)(convf + MATE);
  ushort* vb    = Qb + MATE;
  ushort* convb = vb + MATE;
  ushort* xnb   = convb + MATE;
  ushort* WqT   = xnb + MATE;          // Wq|Wk|Wv transposed, contiguous (N=1536)
  ushort* W2T   = WqT + 3 * 262144;
  ushort* WoT   = W2T + 262144;
  ushort* BcY   = WoT + 262144;        // 5632 x 512 (Bt layout for Y-GEMM)
  float* biasqkv = (float*)(BcY + 5632 * 512);
  float* kmean = biasqkv + 1536;
  float* kvbuf = kmean + 2048;         // 131072 (zeroed)
  float* Sv    = kvbuf + 131072;       // Sv|Skv|Sx contiguous
  float* Skv   = Sv + 2048;
  float* Sx    = Skv + 2048;
  float* Dv    = Sx + 2048;            // Dv|Dkv|Dx contiguous
  float* Dkv   = Dv + 32;
  float* Dx    = Dkv + 32;
  float* ytail = Dx + 32;
  ushort* Ybf  = (ushort*)ytail;       // Y buffer: TC taps x 4096 x 512 bf16

  size_t used_floats = (size_t)(ytail - ws);
  size_t avail_floats = (ws_size / 4 > used_floats) ? (ws_size / 4 - used_floats) : 0;
  int TC = (int)(avail_floats / (MATE / 2));
  if (TC < 1) TC = 1;
  if (TC > 11) TC = 11;

  // all one-time repacks + accumulator zeroing in one launch (memsets folded)
  prep_kernel<<<4490, 256, 0, stream>>>(Wq, Wk, Wv, W2, Wo, Wconv, Q,
                                        bq, bk, bv, WqT, BcY, biasqkv, Qb,
                                        kmean, loss_slot);

  // fused q,k,v: 128x128 tile BK=32, N=1536, grid 12x32 = 384 blocks
  gemm128_qkv<<<dim3(12, 32), 256, 0, stream>>>(Qb, WqT, biasqkv, q0, vb);

  // conv: Y = vb @ Wcat (M=4096, N=5632, K=512), then gather(+bias) -> convb
  if (TC >= 11) {
    gemm_conv<<<dim3(44, 16), 512, 0, stream>>>(vb, BcY, Ybf, 512, 5632);
    gather_add_bias<<<2048, 256, 0, stream>>>(Ybf, adj, bconv, convb);
  } else {
    hipMemsetAsync(convf, 0, MATE * sizeof(float), stream);
    for (int t0 = 0; t0 < 11; t0 += TC) {
      int nt = (11 - t0 < TC) ? (11 - t0) : TC;
      int ncols = nt * 512;
      gemm_conv<<<dim3(ncols / 128, 16), 512, 0, stream>>>(
          vb, BcY + (size_t)(t0 * 512) * 512, Ybf, 512, ncols);
      gather_add<<<4096, 256, 0, stream>>>(Ybf, adj, convf, t0, nt, ncols);
    }
    convbias_cast<<<2048, 256, 0, stream>>>(convf, bconv, convb);
  }

  gemm64<<<dim3(8, 64), 256, 0, stream>>>(convb, W2T, b2, x_local, nullptr, 512);

  // focus on k0 only (q-focus fused into attn_ln)
  focus_kernel<<<TOK_TOTAL, 256, 0, stream>>>(k0, scale_p);

  // kv + fused disagree-v + fused kmean
  kv_kernel<<<256, 256, 0, stream>>>(k0, v, kvbuf, Sv, Dv, kmean);

  // fused q-focus + attention-out + z + LayerNorm + disagree-x + disagree-kv
  attn_ln_kernel<<<512, 512, 0, stream>>>(q0, kvbuf, kmean, x_local, scale_p,
                                          ln_g, ln_b, xnb, Sx, Dx, Skv, Dkv);

  disagree_final_all<<<96, 64, 0, stream>>>(Sv, Dv,
                                            1.f / (33554432.f * 3.f),
                                            1.f / (131072.f * 3.f),
                                            1.f / (33554432.f * 3.f), loss_slot);

  gemm64<<<dim3(8, 64), 256, 0, stream>>>(xnb, WoT, bo, out, nullptr, 512);
}

// Round 14
// 282.253 us; speedup vs baseline: 1.1792x; 1.0127x over previous
//
#include <hip/hip_runtime.h>
#include <math.h>

// Problem constants: B=4, N=1024, C=512, K=10, H=8, d=64
#define TOK_TOTAL 4096          // B*N
#define KNB 10
#define MATE 2097152            // 4096*512 elements

typedef __attribute__((ext_vector_type(8))) short short8;
typedef __attribute__((ext_vector_type(4))) float floatx4;
typedef unsigned short ushort;

__device__ __forceinline__ floatx4 mfma16(short8 a, short8 b, floatx4 c) {
  return __builtin_amdgcn_mfma_f32_16x16x32_bf16(a, b, c, 0, 0, 0);
}

__device__ __forceinline__ ushort f2bf(float f) {
  union { float f; unsigned int u; } x; x.f = f;
  unsigned int r = x.u + 0x7fffu + ((x.u >> 16) & 1u);
  return (ushort)(r >> 16);
}

__device__ __forceinline__ float bf2f(ushort u) {
  union { unsigned int u; float f; } x; x.u = ((unsigned int)u) << 16;
  return x.f;
}

__device__ __forceinline__ float lane_bcast(float v, int l) {
  union { float f; int i; } x; x.f = v;
  x.i = __builtin_amdgcn_readlane(x.i, l);
  return x.f;
}

// async global->LDS DMA, 16B/lane; LDS dest = wave-uniform base + lane*16
__device__ __forceinline__ void glds16(const ushort* g, ushort* l) {
  __builtin_amdgcn_global_load_lds((const __attribute__((address_space(1))) void*)g,
                                   (__attribute__((address_space(3))) void*)l, 16, 0, 0);
}

__device__ __forceinline__ float wave_reduce_sum(float v) {
#pragma unroll
  for (int m = 32; m >= 1; m >>= 1) v += __shfl_xor(v, m, 64);
  return v;
}

__device__ __forceinline__ float block_reduce_sum_256(float v, float* red) {
  v = wave_reduce_sum(v);
  __syncthreads();
  if ((threadIdx.x & 63) == 0) red[threadIdx.x >> 6] = v;
  __syncthreads();
  return red[0] + red[1] + red[2] + red[3];
}

// ---------------- one prep kernel: 5 weight transposes | wconv repack | bias pack |
// Q cast | accumulator-zeroing (folds the two hipMemsetAsync dispatches)
__global__ __launch_bounds__(256) void prep_kernel(const float* __restrict__ Wq,
                                                   const float* __restrict__ Wk,
                                                   const float* __restrict__ Wv,
                                                   const float* __restrict__ W2p,
                                                   const float* __restrict__ Wo,
                                                   const float* __restrict__ Wconv,
                                                   const float* __restrict__ Q,
                                                   const float* __restrict__ bq,
                                                   const float* __restrict__ bk,
                                                   const float* __restrict__ bv,
                                                   ushort* __restrict__ WT,   // 5x512x512
                                                   ushort* __restrict__ BcY,  // 5632x512
                                                   float* __restrict__ biasqkv,
                                                   ushort* __restrict__ Qb,
                                                   float* __restrict__ zbase, // kmean..Dx, 139360 f
                                                   float* __restrict__ loss) {
  int blk = blockIdx.x;
  if (blk < 1280) {
    __shared__ float tile[32][33];
    int zz = blk >> 8, rem = blk & 255;
    const float* W = (zz == 0) ? Wq : (zz == 1) ? Wk : (zz == 2) ? Wv
                     : (zz == 3) ? W2p : Wo;
    ushort* Wt = WT + (size_t)zz * 262144;
    int n0 = (rem & 15) * 32, k0 = (rem >> 4) * 32;
    int tx = threadIdx.x & 31, ty = threadIdx.x >> 5;  // 32 x 8
#pragma unroll
    for (int i = 0; i < 32; i += 8)
      tile[ty + i][tx] = W[(size_t)(k0 + ty + i) * 512 + n0 + tx];
    __syncthreads();
#pragma unroll
    for (int i = 0; i < 32; i += 8)
      Wt[(size_t)(n0 + ty + i) * 512 + k0 + tx] = f2bf(tile[tx][ty + i]);
  } else if (blk < 2304) {
    int i = (blk - 1280) * 256 + threadIdx.x;  // o*512+c
    const float* src = Wconv + (size_t)i * 11;
    int o = i >> 9, c = i & 511;
#pragma unroll
    for (int t = 0; t < 11; ++t)
      BcY[(((size_t)(t * 512 + o)) << 9) + c] = f2bf(src[t]);
  } else if (blk == 2304) {
    for (int i = threadIdx.x; i < 1536; i += 256)
      biasqkv[i] = (i < 512) ? bq[i] : ((i < 1024) ? bk[i - 512] : bv[i - 1024]);
  } else if (blk < 4353) {
    int i = (blk - 2305) * 256 + threadIdx.x;  // x4 floats
    float4 v = *(const float4*)(Q + (size_t)i * 4);
    Qb[(size_t)i * 4 + 0] = f2bf(v.x);
    Qb[(size_t)i * 4 + 1] = f2bf(v.y);
    Qb[(size_t)i * 4 + 2] = f2bf(v.z);
    Qb[(size_t)i * 4 + 3] = f2bf(v.w);
  } else {
    // zero kmean|kvbuf|Sv|Skv|Sx|Dv|Dkv|Dx (139360 floats = 34840 float4)
    int i = (blk - 4353) * 256 + threadIdx.x;
    if (i < 34840) {
      float4 z; z.x = 0.f; z.y = 0.f; z.z = 0.f; z.w = 0.f;
      ((float4*)zbase)[i] = z;
    }
    if (blk == 4353 && threadIdx.x == 0) loss[0] = 0.f;
  }
}

// ============ gemm_conv v8: BM=BN=256, BK=32; 1024 thr = 16 waves (4x4),
// wave 64x64 (acc[4][4] = 64 VGPR -- NO occupancy cliff; fragment<->lane mapping
// unchanged). R13 confirmed short-K amortization: BM 128->256 gave -10%. This
// widens BN too: staging/output -33% vs v7 (32KB per 64K-elem step), blocks
// halve to 352 = ALL co-resident at 2 blk/CU (no tail wave). 32 slabs x 512
// (A 0..15, B 16..31); wave w stages slabs 2w, 2w+1. Proven 2-buffer
// __syncthreads schedule (R4). LDS 64KB.
__global__ __launch_bounds__(1024, 2) void gemm_conv(const ushort* __restrict__ A,
                                                     const ushort* __restrict__ Bt,
                                                     ushort* __restrict__ Cb,
                                                     int Ktot, int Ncols) {
  __shared__ __align__(16) ushort SS[2][16384];  // 32 slabs x 512
  int tid = threadIdx.x, w = tid >> 6, lane = tid & 63;
  int lm = lane & 15, kq = lane >> 4;
  int row0 = blockIdx.y * 256, col0 = blockIdx.x * 256;
  int wm = w >> 2, wn = w & 3;   // 4x4 wave grid over 256x256

  const ushort* gs[2];
  int go[2];
#pragma unroll
  for (int i = 0; i < 2; ++i) {
    int slab = 2 * w + i;
    const ushort* base = (slab < 16)
        ? (A + (size_t)(row0 + slab * 16 + lm) * Ktot)
        : (Bt + (size_t)(col0 + (slab - 16) * 16 + lm) * Ktot);
    gs[i] = base + kq * 8;
    go[i] = slab * 512;
  }

  floatx4 acc[4][4];
#pragma unroll
  for (int i = 0; i < 4; ++i)
#pragma unroll
    for (int j = 0; j < 4; ++j)
#pragma unroll
      for (int e = 0; e < 4; ++e) acc[i][j][e] = 0.f;

#pragma unroll
  for (int i = 0; i < 2; ++i) glds16(gs[i], SS[0] + go[i]);

  int nsteps = Ktot >> 5;  // K=512 -> 16
  for (int s = 0; s < nsteps; ++s) {
    int buf = s & 1;
    __syncthreads();
    if (s + 1 < nsteps) {
      int koff = (s + 1) << 5;
      ushort* dst = SS[buf ^ 1];
#pragma unroll
      for (int i = 0; i < 2; ++i) glds16(gs[i] + koff, dst + go[i]);
    }
    short8 a[4], b[4];
#pragma unroll
    for (int mt = 0; mt < 4; ++mt)
      a[mt] = *(const short8*)(&SS[buf][(wm * 4 + mt) * 512 + lane * 8]);
#pragma unroll
    for (int nt = 0; nt < 4; ++nt)
      b[nt] = *(const short8*)(&SS[buf][8192 + (wn * 4 + nt) * 512 + lane * 8]);
#pragma unroll
    for (int mt = 0; mt < 4; ++mt)
#pragma unroll
      for (int nt = 0; nt < 4; ++nt)
        acc[mt][nt] = mfma16(a[mt], b[nt], acc[mt][nt]);
  }

#pragma unroll
  for (int mt = 0; mt < 4; ++mt) {
#pragma unroll
    for (int nt = 0; nt < 4; ++nt) {
      int col = col0 + wn * 64 + nt * 16 + lm;
#pragma unroll
      for (int r = 0; r < 4; ++r) {
        int row = row0 + wm * 64 + mt * 16 + kq * 4 + r;
        Cb[(size_t)row * Ncols + col] = f2bf(acc[mt][nt][r]);
      }
    }
  }
}

// ============ gemm128_qkv v3 (proven, R4): BK=32, N=1536 fixed, K=512 (16 steps)
__global__ __launch_bounds__(256, 4) void gemm128_qkv(const ushort* __restrict__ A,
                                                      const ushort* __restrict__ Bt,
                                                      const float* __restrict__ bias,
                                                      float* __restrict__ outf,
                                                      ushort* __restrict__ vb) {
  __shared__ __align__(16) ushort As[2][4096];
  __shared__ __align__(16) ushort Bs[2][4096];
  int tid = threadIdx.x, w = tid >> 6, lane = tid & 63;
  int lm = lane & 15, kq = lane >> 4;
  int row0 = blockIdx.y * 128, col0 = blockIdx.x * 128;
  int wm = w >> 1, wn = w & 1;

  bool isA = (w < 2);
  const ushort* gs[4];
  int go[4];
#pragma unroll
  for (int i = 0; i < 4; ++i) {
    int slab = (w & 1) * 4 + i;
    const ushort* base = isA ? (A + (size_t)(row0 + slab * 16 + lm) * 512)
                             : (Bt + (size_t)(col0 + slab * 16 + lm) * 512);
    gs[i] = base + kq * 8;
    go[i] = slab * 512;
  }

  floatx4 acc[4][4];
#pragma unroll
  for (int i = 0; i < 4; ++i)
#pragma unroll
    for (int j = 0; j < 4; ++j)
#pragma unroll
      for (int e = 0; e < 4; ++e) acc[i][j][e] = 0.f;

#pragma unroll
  for (int i = 0; i < 4; ++i)
    glds16(gs[i], (isA ? As[0] : Bs[0]) + go[i]);

  for (int s = 0; s < 16; ++s) {
    int buf = s & 1;
    __syncthreads();
    if (s + 1 < 16) {
      int koff = (s + 1) << 5;
      ushort* dst = (isA ? As[buf ^ 1] : Bs[buf ^ 1]);
#pragma unroll
      for (int i = 0; i < 4; ++i) glds16(gs[i] + koff, dst + go[i]);
    }
    short8 a[4], b[4];
#pragma unroll
    for (int mt = 0; mt < 4; ++mt)
      a[mt] = *(const short8*)(&As[buf][(wm * 4 + mt) * 512 + lane * 8]);
#pragma unroll
    for (int nt = 0; nt < 4; ++nt)
      b[nt] = *(const short8*)(&Bs[buf][(wn * 4 + nt) * 512 + lane * 8]);
#pragma unroll
    for (int mt = 0; mt < 4; ++mt)
#pragma unroll
      for (int nt = 0; nt < 4; ++nt)
        acc[mt][nt] = mfma16(a[mt], b[nt], acc[mt][nt]);
  }

#pragma unroll
  for (int mt = 0; mt < 4; ++mt) {
#pragma unroll
    for (int nt = 0; nt < 4; ++nt) {
      int col = col0 + wn * 64 + nt * 16 + lm;  // 0..1535
      int mat = col >> 9, cc = col & 511;
      float bs = bias[col];
#pragma unroll
      for (int r = 0; r < 4; ++r) {
        int row = row0 + wm * 64 + mt * 16 + kq * 4 + r;
        float val = acc[mt][nt][r] + bs;
        size_t idx = (size_t)row * 512 + cc;
        outf[(size_t)mat * MATE + idx] = val;
        if (mat == 2) vb[idx] = f2bf(val);
      }
    }
  }
}

// ---------------- conv gather: 2 rows/block, uint2 (4 bf16) per thread
__global__ __launch_bounds__(256) void gather_add_bias(const ushort* __restrict__ Y,
                                                       const int* __restrict__ adj,
                                                       const float* __restrict__ bias,
                                                       ushort* __restrict__ convb) {
  int n = (blockIdx.x << 1) + (threadIdx.x >> 7);
  int b10 = (n >> 10) << 10;
  int o = (threadIdx.x & 127) << 2;
  float4 bs = *(const float4*)(bias + o);
  float a0 = bs.x, a1 = bs.y, a2 = bs.z, a3 = bs.w;
#pragma unroll
  for (int t = 0; t < 11; ++t) {
    int src = (t == 0) ? n : (b10 + adj[(size_t)n * KNB + (t - 1)]);
    const ushort* p = Y + (size_t)src * 5632 + (size_t)t * 512 + o;
    uint2 u = *(const uint2*)p;
    a0 += bf2f((ushort)(u.x & 0xffff));
    a1 += bf2f((ushort)(u.x >> 16));
    a2 += bf2f((ushort)(u.y & 0xffff));
    a3 += bf2f((ushort)(u.y >> 16));
  }
  uint2 w;
  w.x = (unsigned)f2bf(a0) | ((unsigned)f2bf(a1) << 16);
  w.y = (unsigned)f2bf(a2) | ((unsigned)f2bf(a3) << 16);
  *(uint2*)(convb + (size_t)n * 512 + o) = w;
}

// ---------------- fallback chunked gather (TC<11): accumulate f32
__global__ __launch_bounds__(256) void gather_add(const ushort* __restrict__ Y,
                                                  const int* __restrict__ adj,
                                                  float* __restrict__ convf,
                                                  int t0, int ntaps, int ncols) {
  int n = blockIdx.x;
  int b10 = (n >> 10) << 10;
  int o = threadIdx.x * 2;
  float a0 = 0.f, a1 = 0.f;
  for (int t = t0; t < t0 + ntaps; ++t) {
    int src = (t == 0) ? n : (b10 + adj[(size_t)n * KNB + (t - 1)]);
    const ushort* p = Y + (size_t)src * ncols + (size_t)(t - t0) * 512 + o;
    a0 += bf2f(p[0]);
    a1 += bf2f(p[1]);
  }
  convf[(size_t)n * 512 + o] += a0;
  convf[(size_t)n * 512 + o + 1] += a1;
}

__global__ __launch_bounds__(256) void convbias_cast(const float* __restrict__ cf,
                                                     const float* __restrict__ bias,
                                                     ushort* __restrict__ cb) {
  int i = blockIdx.x * 256 + threadIdx.x;
  float4 v = *(const float4*)(cf + (size_t)i * 4);
  int c = (i * 4) & 511;
  cb[(size_t)i * 4 + 0] = f2bf(v.x + bias[c + 0]);
  cb[(size_t)i * 4 + 1] = f2bf(v.y + bias[c + 1]);
  cb[(size_t)i * 4 + 2] = f2bf(v.z + bias[c + 2]);
  cb[(size_t)i * 4 + 3] = f2bf(v.w + bias[c + 3]);
}

// ============ gemm64: BM=64,BN=64,BK=64; 4 waves (2x2), wave 32x32 ============
__global__ __launch_bounds__(256) void gemm64(const ushort* __restrict__ A,
                                              const ushort* __restrict__ Bt,
                                              const float* __restrict__ bias,
                                              float* __restrict__ Cf,
                                              ushort* __restrict__ Cb,
                                              int Ktot) {
  __shared__ __align__(16) ushort As[2][4096];
  __shared__ __align__(16) ushort Bs[2][4096];
  int tid = threadIdx.x, w = tid >> 6, lane = tid & 63;
  int lm = lane & 15, kq = lane >> 4;
  int row0 = blockIdx.y * 64, col0 = blockIdx.x * 64;
  int wm = w >> 1, wn = w & 1;

  const ushort* gsrc[4];
  int goff[4];
  bool isA = (w < 2);
#pragma unroll
  for (int i = 0; i < 4; ++i) {
    int l = w * 4 + i, t, j;
    const ushort* base;
    if (l < 8) { t = l >> 1; j = l & 1; base = A + (size_t)(row0 + t * 16 + lm) * Ktot; }
    else { int lb = l - 8; t = lb >> 1; j = lb & 1; base = Bt + (size_t)(col0 + t * 16 + lm) * Ktot; }
    gsrc[i] = base + j * 32 + kq * 8;
    goff[i] = t * 1024 + j * 512;
  }

  floatx4 acc[2][2];
#pragma unroll
  for (int i = 0; i < 2; ++i)
#pragma unroll
    for (int j = 0; j < 2; ++j)
#pragma unroll
      for (int e = 0; e < 4; ++e) acc[i][j][e] = 0.f;

#pragma unroll
  for (int i = 0; i < 4; ++i)
    glds16(gsrc[i], (isA ? As[0] : Bs[0]) + goff[i]);

  int nsteps = Ktot >> 6;
  for (int s = 0; s < nsteps; ++s) {
    int buf = s & 1;
    __syncthreads();
    if (s + 1 < nsteps) {
      int koff = (s + 1) << 6;
      ushort* dst = (isA ? As[buf ^ 1] : Bs[buf ^ 1]);
#pragma unroll
      for (int i = 0; i < 4; ++i) glds16(gsrc[i] + koff, dst + goff[i]);
    }
#pragma unroll
    for (int j = 0; j < 2; ++j) {
      short8 a0 = *(const short8*)(&As[buf][(wm * 2 + 0) * 1024 + j * 512 + lane * 8]);
      short8 a1 = *(const short8*)(&As[buf][(wm * 2 + 1) * 1024 + j * 512 + lane * 8]);
      short8 b0 = *(const short8*)(&Bs[buf][(wn * 2 + 0) * 1024 + j * 512 + lane * 8]);
      short8 b1 = *(const short8*)(&Bs[buf][(wn * 2 + 1) * 1024 + j * 512 + lane * 8]);
      acc[0][0] = mfma16(a0, b0, acc[0][0]);
      acc[0][1] = mfma16(a0, b1, acc[0][1]);
      acc[1][0] = mfma16(a1, b0, acc[1][0]);
      acc[1][1] = mfma16(a1, b1, acc[1][1]);
    }
  }

  int colb = col0 + wn * 32;
  int rowb = row0 + wm * 32 + kq * 4;
#pragma unroll
  for (int mt = 0; mt < 2; ++mt) {
#pragma unroll
    for (int nt = 0; nt < 2; ++nt) {
      int col = colb + nt * 16 + lm;
      float bs = bias[col];
#pragma unroll
      for (int r = 0; r < 4; ++r) {
        int row = rowb + mt * 16 + r;
        float val = acc[mt][nt][r] + bs;
        size_t idx = (size_t)row * 512 + col;
        if (Cf) Cf[idx] = val;
        if (Cb) Cb[idx] = f2bf(val);
      }
    }
  }
}

// ---------------- relu+eps, /softplus(scale), focus (in-place) — k0 ONLY
__global__ __launch_bounds__(256) void focus_kernel(float* __restrict__ x,
                                                    const float* __restrict__ scale_p) {
  __shared__ float red[4];
  int row = blockIdx.x;
  float* p = x + (size_t)row * 512;
  int tid = threadIdx.x;
  float sp0 = scale_p[tid], sp1 = scale_p[tid + 256];
  float sc0 = sp0 > 20.f ? sp0 : log1pf(expf(sp0));
  float sc1 = sp1 > 20.f ? sp1 : log1pf(expf(sp1));
  float v0 = (fmaxf(p[tid], 0.f) + 1e-6f) / sc0;
  float v1 = (fmaxf(p[tid + 256], 0.f) + 1e-6f) / sc1;
  float tot = block_reduce_sum_256(v0 * v0 + v1 * v1, red);
  float n = sqrtf(tot);
  float np = n + 1e-6f;
  float f = n / (np * np * np);
  p[tid] = v0 * v0 * v0 * f;
  p[tid + 256] = v1 * v1 * v1 * f;
}

// ---------------- kv split-K x8 (256 blocks) + fused disagree-v + fused kmean
__global__ __launch_bounds__(256) void kv_kernel(const float* __restrict__ kf,
                                                 const float* __restrict__ v,
                                                 float* __restrict__ kv,
                                                 float* __restrict__ Sacc,
                                                 float* __restrict__ Dacc,
                                                 float* __restrict__ kmean) {
  __shared__ float Ks[16][64];
  __shared__ float Vs[16][64];
  __shared__ float Spart[64];
  __shared__ float Kpart[64];
  __shared__ float Dpart;
  int bh = blockIdx.x >> 3, chunk = blockIdx.x & 7;
  int b = bh >> 3, h = bh & 7;
  int tid = threadIdx.x;
  int lr = tid >> 4, lc = (tid & 15) << 2;
  int tx = tid & 15, ty = tid >> 4;
  if (tid < 64) { Spart[tid] = 0.f; Kpart[tid] = 0.f; }
  if (tid == 0) Dpart = 0.f;
  __syncthreads();
  const float* kbase = kf + (size_t)b * 524288 + h * 64 + (size_t)chunk * 128 * 512;
  const float* vbase = v + (size_t)b * 524288 + h * 64 + (size_t)chunk * 128 * 512;
  float acc[4][4] = {};
  float Sloc[4] = {0.f, 0.f, 0.f, 0.f};
  float Kloc[4] = {0.f, 0.f, 0.f, 0.f};
  float Dloc = 0.f;
  for (int n0 = 0; n0 < 128; n0 += 16) {
    float4 ke = *(const float4*)(kbase + (size_t)(n0 + lr) * 512 + lc);
    *(float4*)(&Ks[lr][lc]) = ke;
    Kloc[0] += ke.x; Kloc[1] += ke.y; Kloc[2] += ke.z; Kloc[3] += ke.w;
    float4 ve = *(const float4*)(vbase + (size_t)(n0 + lr) * 512 + lc);
    *(float4*)(&Vs[lr][lc]) = ve;
    __syncthreads();
    // disagree-v on this tile: 16-lane group reduce (threads sharing row lr)
    float sq = ve.x * ve.x + ve.y * ve.y + ve.z * ve.z + ve.w * ve.w;
#pragma unroll
    for (int m = 1; m < 16; m <<= 1) sq += __shfl_xor(sq, m, 64);
    float cn = fmaxf(sqrtf(sq), 1e-12f);
    Sloc[0] += ve.x / cn; Sloc[1] += ve.y / cn;
    Sloc[2] += ve.z / cn; Sloc[3] += ve.w / cn;
    if ((tid & 15) == 0) Dloc += sq / (cn * cn);
#pragma unroll
    for (int kk = 0; kk < 16; ++kk) {
      float a[4], bb[4];
#pragma unroll
      for (int i = 0; i < 4; ++i) a[i] = Ks[kk][ty * 4 + i];
#pragma unroll
      for (int j = 0; j < 4; ++j) bb[j] = Vs[kk][tx * 4 + j];
#pragma unroll
      for (int i = 0; i < 4; ++i)
#pragma unroll
        for (int j = 0; j < 4; ++j) acc[i][j] += a[i] * bb[j];
    }
    __syncthreads();
  }
#pragma unroll
  for (int i = 0; i < 4; ++i)
#pragma unroll
    for (int j = 0; j < 4; ++j)
      atomicAdd(&kv[(size_t)bh * 4096 + (ty * 4 + i) * 64 + tx * 4 + j],
                acc[i][j] * (1.f / 1024.f));
  // accumulate disagree-v + kmean partials: LDS then one global set
#pragma unroll
  for (int i = 0; i < 4; ++i) {
    atomicAdd(&Spart[lc + i], Sloc[i]);
    atomicAdd(&Kpart[lc + i], Kloc[i]);
  }
  if ((tid & 15) == 0) atomicAdd(&Dpart, Dloc);
  __syncthreads();
  if (tid < 64) {
    atomicAdd(&Sacc[bh * 64 + tid], Spart[tid]);
    atomicAdd(&kmean[b * 512 + h * 64 + tid], Kpart[tid] * (1.f / 1024.f));
  }
  if (tid == 64) atomicAdd(&Dacc[bh], Dpart);
}

// ---------------- fused q-focus + attn-out + z + LN + disagree-x (+disagree-kv)
__global__ __launch_bounds__(512, 4) void attn_ln_kernel(const float* __restrict__ qf,
                                                         const float* __restrict__ kvf,
                                                         const float* __restrict__ kmean,
                                                         const float* __restrict__ x_local,
                                                         const float* __restrict__ scale_p,
                                                         const float* __restrict__ g,
                                                         const float* __restrict__ bp,
                                                         ushort* __restrict__ xn,
                                                         float* __restrict__ Sacc,
                                                         float* __restrict__ Dacc,
                                                         float* __restrict__ Skv,
                                                         float* __restrict__ Dkv) {
  __shared__ __align__(16) ushort kvs[32768];  // [h][dd][e] bf16, 64 KB
  __shared__ float red[16];                    // 8 sums | 8 sumsqs
  __shared__ float Sl[8][64];
  __shared__ float Dl[8];
  int r0 = blockIdx.x << 3;       // first of 8 rows
  int b = r0 >> 10;
  int c = threadIdx.x, wv = c >> 6, lane = c & 63;
  // stage kv[b] f32 -> bf16 LDS (32768 elems), coalesced float4
  const float4* kvg = (const float4*)(kvf + (size_t)b * 32768);
#pragma unroll
  for (int i = 0; i < 16; ++i) {
    float4 kvv = kvg[c + i * 512];
    int o = (c + i * 512) << 2;
    kvs[o + 0] = f2bf(kvv.x); kvs[o + 1] = f2bf(kvv.y);
    kvs[o + 2] = f2bf(kvv.z); kvs[o + 3] = f2bf(kvv.w);
  }
  float kmr = kmean[b * 512 + c];
  float gr = g[c], bpr = bp[c];
  float sp = scale_p[c];
  float sc = sp > 20.f ? sp : log1pf(expf(sp));
  float scinv = 1.f / sc;
  __syncthreads();
  // one-time: pull this thread's kv column, packed 2 bf16 per uint (32 VGPRs)
  unsigned int kvr[32];
#pragma unroll
  for (int i = 0; i < 32; ++i) {
    unsigned int lo = kvs[wv * 4096 + (2 * i) * 64 + lane];
    unsigned int hi = kvs[wv * 4096 + (2 * i + 1) * 64 + lane];
    kvr[i] = lo | (hi << 16);
  }
  float Sreg = 0.f, Dreg = 0.f;
  for (int r = 0; r < 8; ++r) {
    int row = r0 + r;
    float qraw = qf[(size_t)row * 512 + c];
    float xl = x_local[(size_t)row * 512 + c];
    // ---- fused q-focus: v0 = (relu(q)+eps)/softplus(scale); row-norm; cube
    float v0 = (fmaxf(qraw, 0.f) + 1e-6f) * scinv;
    float l2 = wave_reduce_sum(v0 * v0);
    if (lane == 0) red[wv] = l2;
    __syncthreads();
    float nq2 = red[0] + red[1] + red[2] + red[3] + red[4] + red[5] + red[6] + red[7];
    __syncthreads();
    float nq = sqrtf(nq2);
    float npq = nq + 1e-6f;
    float qv = v0 * v0 * v0 * (nq / (npq * npq * npq));
    // z = 1/(dot(q_head, kmean_head)+eps), per wave
    float zd = wave_reduce_sum(qv * kmr);
    float zz = 1.f / (zd + 1e-6f);
    // dot via readlane broadcast + packed register kv column — no LDS
    float s = 0.f;
#pragma unroll
    for (int i = 0; i < 32; ++i) {
      union { unsigned int u; float f; } lo, hi;
      lo.u = kvr[i] << 16;
      hi.u = kvr[i] & 0xffff0000u;
      s += lane_bcast(qv, 2 * i) * lo.f;
      s += lane_bcast(qv, 2 * i + 1) * hi.f;
    }
    float xv = s * zz + xl;
    // single-pass LN stats: block sum + sumsq
    float s1 = wave_reduce_sum(xv);
    float s2 = wave_reduce_sum(xv * xv);       // also the sub-vector norm^2
    if (lane == 0) { red[wv] = s1; red[8 + wv] = s2; }
    __syncthreads();
    float tsum = red[0] + red[1] + red[2] + red[3] + red[4] + red[5] + red[6] + red[7];
    float tsq = red[8] + red[9] + red[10] + red[11] + red[12] + red[13] + red[14] + red[15];
    __syncthreads();                           // red consumed before next row
    float mu = tsum * (1.f / 512.f);
    float var = tsq * (1.f / 512.f) - mu * mu;
    float inv = rsqrtf(fmaxf(var, 0.f) + 1e-5f);
    xn[(size_t)row * 512 + c] = f2bf((xv - mu) * inv * gr + bpr);
    // disagreement on x
    float norm = fmaxf(sqrtf(s2), 1e-12f);
    Sreg += xv / norm;
    Dreg += s2 / (norm * norm);
  }
  Sl[wv][lane] = Sreg;
  if (lane == 0) Dl[wv] = Dreg;
  __syncthreads();
  int gx = b * 8 + ((r0 & 1023) >> 7);
  if (c < 64) {
    float ssum = 0.f;
#pragma unroll
    for (int ww = 0; ww < 8; ++ww) ssum += Sl[ww][c];
    atomicAdd(&Sacc[gx * 64 + c], ssum);
  } else if (c == 64) {
    float dsum = 0.f;
#pragma unroll
    for (int ww = 0; ww < 8; ++ww) dsum += Dl[ww];
    atomicAdd(&Dacc[gx], dsum);
  }
  // disagree-kv: one block per batch; wave wv = head; vals from packed regs
  if ((blockIdx.x & 127) == 0) {
    float S2 = 0.f, D2 = 0.f;
#pragma unroll
    for (int i = 0; i < 32; ++i) {
      union { unsigned int u; float f; } lo, hi;
      lo.u = kvr[i] << 16;
      hi.u = kvr[i] & 0xffff0000u;
      float sq = wave_reduce_sum(lo.f * lo.f);
      float nrm = fmaxf(sqrtf(sq), 1e-12f);
      float hn = lo.f / nrm;
      S2 += hn; D2 += hn * hn;
      sq = wave_reduce_sum(hi.f * hi.f);
      nrm = fmaxf(sqrtf(sq), 1e-12f);
      hn = hi.f / nrm;
      S2 += hn; D2 += hn * hn;
    }
    float dt = wave_reduce_sum(D2);
    atomicAdd(&Skv[(b * 8 + wv) * 64 + lane], S2);
    if (lane == 0) atomicAdd(&Dkv[b * 8 + wv], dt);
  }
}

// ---------------- disagreement finals, all 3 sets in parallel (96 blocks)
__global__ __launch_bounds__(64) void disagree_final_all(const float* __restrict__ Sall,
                                                         const float* __restrict__ Dall,
                                                         float s0, float s1, float s2,
                                                         float* __restrict__ loss) {
  int set = blockIdx.x >> 5, gg = blockIdx.x & 31;
  int l = threadIdx.x;
  float sv = Sall[set * 2048 + gg * 64 + l];
  float sim = wave_reduce_sum(sv * sv);
  if (l == 0) {
    float scale = (set == 0) ? s0 : (set == 1) ? s1 : s2;
    atomicAdd(loss, (sim - Dall[set * 32 + gg]) * scale);
  }
}

extern "C" void kernel_launch(void* const* d_in, const int* in_sizes, int n_in,
                              void* d_out, int out_size, void* d_ws, size_t ws_size,
                              hipStream_t stream) {
  const float* Q       = (const float*)d_in[0];
  const int*   adj     = (const int*)d_in[1];
  const float* Wq      = (const float*)d_in[2];
  const float* bq      = (const float*)d_in[3];
  const float* Wk      = (const float*)d_in[4];
  const float* bk      = (const float*)d_in[5];
  const float* Wv      = (const float*)d_in[6];
  const float* bv      = (const float*)d_in[7];
  const float* scale_p = (const float*)d_in[8];
  const float* Wconv   = (const float*)d_in[9];
  const float* bconv   = (const float*)d_in[10];
  const float* W2      = (const float*)d_in[11];
  const float* b2      = (const float*)d_in[12];
  const float* ln_g    = (const float*)d_in[13];
  const float* ln_b    = (const float*)d_in[14];
  const float* Wo      = (const float*)d_in[15];
  const float* bo      = (const float*)d_in[16];

  float* out = (float*)d_out;
  float* loss_slot = out + MATE;

  float* ws = (float*)d_ws;
  float* q0      = ws;                 // f32; k0, v contiguous (qkv fused epilogue)
  float* k0      = q0 + MATE;
  float* v       = k0 + MATE;
  float* x_local = v + MATE;
  float* convf   = x_local + MATE;     // fallback accum only (TC<11)
  ushort* Qb    = (ushort*)(convf + MATE);
  ushort* vb    = Qb + MATE;
  ushort* convb = vb + MATE;
  ushort* xnb   = convb + MATE;
  ushort* WqT   = xnb + MATE;          // Wq|Wk|Wv transposed, contiguous (N=1536)
  ushort* W2T   = WqT + 3 * 262144;
  ushort* WoT   = W2T + 262144;
  ushort* BcY   = WoT + 262144;        // 5632 x 512 (Bt layout for Y-GEMM)
  float* biasqkv = (float*)(BcY + 5632 * 512);
  float* kmean = biasqkv + 1536;
  float* kvbuf = kmean + 2048;         // 131072 (zeroed)
  float* Sv    = kvbuf + 131072;       // Sv|Skv|Sx contiguous
  float* Skv   = Sv + 2048;
  float* Sx    = Skv + 2048;
  float* Dv    = Sx + 2048;            // Dv|Dkv|Dx contiguous
  float* Dkv   = Dv + 32;
  float* Dx    = Dkv + 32;
  float* ytail = Dx + 32;
  ushort* Ybf  = (ushort*)ytail;       // Y buffer: TC taps x 4096 x 512 bf16

  size_t used_floats = (size_t)(ytail - ws);
  size_t avail_floats = (ws_size / 4 > used_floats) ? (ws_size / 4 - used_floats) : 0;
  int TC = (int)(avail_floats / (MATE / 2));
  if (TC < 1) TC = 1;
  if (TC > 11) TC = 11;

  // all one-time repacks + accumulator zeroing in one launch (memsets folded)
  prep_kernel<<<4490, 256, 0, stream>>>(Wq, Wk, Wv, W2, Wo, Wconv, Q,
                                        bq, bk, bv, WqT, BcY, biasqkv, Qb,
                                        kmean, loss_slot);

  // fused q,k,v: 128x128 tile BK=32, N=1536, grid 12x32 = 384 blocks
  gemm128_qkv<<<dim3(12, 32), 256, 0, stream>>>(Qb, WqT, biasqkv, q0, vb);

  // conv: Y = vb @ Wcat (M=4096, N=5632, K=512), then gather(+bias) -> convb
  if (TC >= 11) {
    gemm_conv<<<dim3(22, 16), 1024, 0, stream>>>(vb, BcY, Ybf, 512, 5632);
    gather_add_bias<<<2048, 256, 0, stream>>>(Ybf, adj, bconv, convb);
  } else {
    hipMemsetAsync(convf, 0, MATE * sizeof(float), stream);
    for (int t0 = 0; t0 < 11; t0 += TC) {
      int nt = (11 - t0 < TC) ? (11 - t0) : TC;
      int ncols = nt * 512;
      gemm_conv<<<dim3(ncols / 256, 16), 1024, 0, stream>>>(
          vb, BcY + (size_t)(t0 * 512) * 512, Ybf, 512, ncols);
      gather_add<<<4096, 256, 0, stream>>>(Ybf, adj, convf, t0, nt, ncols);
    }
    convbias_cast<<<2048, 256, 0, stream>>>(convf, bconv, convb);
  }

  gemm64<<<dim3(8, 64), 256, 0, stream>>>(convb, W2T, b2, x_local, nullptr, 512);

  // focus on k0 only (q-focus fused into attn_ln)
  focus_kernel<<<TOK_TOTAL, 256, 0, stream>>>(k0, scale_p);

  // kv + fused disagree-v + fused kmean
  kv_kernel<<<256, 256, 0, stream>>>(k0, v, kvbuf, Sv, Dv, kmean);

  // fused q-focus + attention-out + z + LayerNorm + disagree-x + disagree-kv
  attn_ln_kernel<<<512, 512, 0, stream>>>(q0, kvbuf, kmean, x_local, scale_p,
                                          ln_g, ln_b, xnb, Sx, Dx, Skv, Dkv);

  disagree_final_all<<<96, 64, 0, stream>>>(Sv, Dv,
                                            1.f / (33554432.f * 3.f),
                                            1.f / (131072.f * 3.f),
                                            1.f / (33554432.f * 3.f), loss_slot);

  gemm64<<<dim3(8, 64), 256, 0, stream>>>(xnb, WoT, bo, out, nullptr, 512);
}